// Round 4
// baseline (2009.399 us; speedup 1.0000x reference)
//
#include <hip/hip_runtime.h>
#include <math.h>

// ---------------- problem constants ----------------
#define TSTEPS 64
#define NSEQ   32
#define HID    256
#define GROWS  1024
#define FH     40
#define FW     160

// ---------------- workspace layout (float units) ----------------
#define OFF_XG     0u            // [2][1024][2048] f32
#define OFF_RNNB   4194304u      // [2048][1024] bf16 (ushort)
#define OFF_W1FB   5242880u      // l1 fw W_ih bf16 1024x1024
#define OFF_W1BB   5767168u      // l1 bw W_ih bf16
#define OFF_HCAT1  6291456u      // [2048][512] f32
#define OFF_H1     7340032u      // [2048][256] f32
#define OFF_HCAT2  7864320u      // [2048][512] f32
#define OFF_PREDS  8912896u      // [2048][12] f32

typedef __attribute__((ext_vector_type(8))) short short8;
typedef __attribute__((ext_vector_type(4))) float f32x4;
typedef __attribute__((ext_vector_type(4))) unsigned short ushort4v;

static __device__ inline unsigned short bf16c(float x) {
  union { float f; unsigned u; } v; v.f = x;
  unsigned r = v.u + 0x7fff + ((v.u >> 16) & 1);   // RNE
  return (unsigned short)(r >> 16);
}

static __device__ inline float sigm(float x) {
  return __builtin_amdgcn_rcpf(1.0f + __expf(-x));
}
static __device__ inline float tanh_fast(float x) {
  return 1.0f - 2.0f * __builtin_amdgcn_rcpf(1.0f + __expf(2.0f * x));
}

// ---------------- f32 -> bf16 converter ----------------
__global__ __launch_bounds__(256) void cvt_bf16(
    const float* __restrict__ in, unsigned short* __restrict__ out, int n4) {
  int i = blockIdx.x * 256 + threadIdx.x;
  if (i < n4) {
    float4 v = ((const float4*)in)[i];
    ushort4v o;
    o[0] = bf16c(v.x); o[1] = bf16c(v.y); o[2] = bf16c(v.z); o[3] = bf16c(v.w);
    ((ushort4v*)out)[i] = o;
  }
}

// ---------------- ROI max pool -> rnn_in bf16 [t*32+n][c*2+ph] ----------------
__global__ __launch_bounds__(256) void roi_pool_kernel(
    const float* __restrict__ feat, const float* __restrict__ rois,
    unsigned short* __restrict__ rnn) {
  int n  = blockIdx.x;
  int cg = blockIdx.y;
  int tid = threadIdx.x;
  int pw = tid & 63, ph = (tid >> 6) & 1, cl = tid >> 7;
  int c = cg * 2 + cl;

  const float* r = rois + n * 5;
  int bi = (int)r[0];
  int x1 = (int)rintf(r[1] * (float)FW);
  int y1 = (int)rintf(r[2] * (float)FH);
  int x2 = (int)rintf(r[3] * (float)FW);
  int y2 = (int)rintf(r[4] * (float)FH);
  float rw = fmaxf((float)(x2 - x1 + 1), 1.0f);
  float rh = fmaxf((float)(y2 - y1 + 1), 1.0f);
  float bin_h = rh * 0.5f;
  float bin_w = rw * (1.0f / 64.0f);

  int hs = min(max((int)floorf((float)ph * bin_h) + y1, 0), FH);
  int he = min(max((int)ceilf((float)(ph + 1) * bin_h) + y1, 0), FH);
  int wst = min(max((int)floorf((float)pw * bin_w) + x1, 0), FW);
  int wen = min(max((int)ceilf((float)(pw + 1) * bin_w) + x1, 0), FW);

  float m = -1e30f;
  bool nonempty = (hs < he) && (wst < wen);
  const float* f = feat + ((size_t)bi * 512 + c) * (FH * FW);
  for (int h = hs; h < he; ++h) {
    const float* fr = f + h * FW;
    for (int w = wst; w < wen; ++w) m = fmaxf(m, fr[w]);
  }
  float out = nonempty ? m : 0.0f;
  rnn[((size_t)pw * NSEQ + n) * 1024 + c * 2 + ph] = bf16c(out);
}

// ---------------- bf16 MFMA GEMM: C[M][N] f32 = A[M,K]bf16 @ B[N,K]bf16^T + bias(m) ----
// 128x128 tile, BK=32, 256 threads (4 waves, 2x2). LDS row pitch 80B (2-way-free banks).
#define GPITCH 40   // ushorts per LDS row (80 bytes, multiple of 16)
__global__ __launch_bounds__(256) void gemm_bf16(
    const unsigned short* __restrict__ A, const unsigned short* __restrict__ B,
    float* __restrict__ C, int M, int N, int K,
    const float* __restrict__ bias1, const float* __restrict__ bias2) {
  __shared__ unsigned short Al[128 * GPITCH];
  __shared__ unsigned short Bl[128 * GPITCH];
  int m0 = blockIdx.y * 128, n0 = blockIdx.x * 128;
  int tid = threadIdx.x;
  int wid = tid >> 6, l = tid & 63, ln15 = l & 15, kg = l >> 4;
  int wm = wid >> 1, wn = wid & 1;

  f32x4 acc[4][4];
#pragma unroll
  for (int i = 0; i < 4; ++i)
#pragma unroll
    for (int j = 0; j < 4; ++j)
#pragma unroll
      for (int q = 0; q < 4; ++q) acc[i][j][q] = 0.0f;

  for (int k0 = 0; k0 < K; k0 += 32) {
#pragma unroll
    for (int it = 0; it < 2; ++it) {
      int chunk = tid + it * 256;
      int row = chunk >> 2, part = chunk & 3;
      short8 va = *(const short8*)(A + (size_t)(m0 + row) * K + k0 + part * 8);
      *(short8*)(Al + row * GPITCH + part * 8) = va;
      short8 vb = *(const short8*)(B + (size_t)(n0 + row) * K + k0 + part * 8);
      *(short8*)(Bl + row * GPITCH + part * 8) = vb;
    }
    __syncthreads();

    short8 a[4], b[4];
#pragma unroll
    for (int mt = 0; mt < 4; ++mt)
      a[mt] = *(const short8*)(Al + (wm * 64 + mt * 16 + ln15) * GPITCH + kg * 8);
#pragma unroll
    for (int nt = 0; nt < 4; ++nt)
      b[nt] = *(const short8*)(Bl + (wn * 64 + nt * 16 + ln15) * GPITCH + kg * 8);
#pragma unroll
    for (int mt = 0; mt < 4; ++mt)
#pragma unroll
      for (int nt = 0; nt < 4; ++nt)
        acc[mt][nt] = __builtin_amdgcn_mfma_f32_16x16x32_bf16(a[mt], b[nt], acc[mt][nt], 0, 0, 0);
    __syncthreads();
  }

#pragma unroll
  for (int mt = 0; mt < 4; ++mt) {
#pragma unroll
    for (int j = 0; j < 4; ++j) {
      int m = m0 + wm * 64 + mt * 16 + kg * 4 + j;
      float bv = 0.0f;
      if (bias1) bv += bias1[m];
      if (bias2) bv += bias2[m];
#pragma unroll
      for (int nt = 0; nt < 4; ++nt) {
        int n = n0 + wn * 64 + nt * 16 + ln15;
        C[(size_t)m * N + n] = acc[mt][nt][j] + bv;
      }
    }
  }
}

// ---------------- generic f32 GEMM: C[M][N] = A[M,K] * B[N,K]^T + bias ----------------
#define BM 64
#define BN 64
#define BK 16
#define APAD 4
__global__ __launch_bounds__(256) void gemm_nt(
    const float* __restrict__ A, const float* __restrict__ B,
    float* __restrict__ C, int M, int N, int K,
    const float* __restrict__ bm1, const float* __restrict__ bm2,
    const float* __restrict__ bn) {
  __shared__ float As[BK][BM + APAD];
  __shared__ float Bs[BK][BN + APAD];
  int m0 = blockIdx.y * BM, n0 = blockIdx.x * BN;
  int tid = threadIdx.x;
  int tm = tid & 15, tn = tid >> 4;
  float acc[4][4] = {};

  int lrow = tid >> 2;
  int lkq = (tid & 3) * 4;

  for (int k0 = 0; k0 < K; k0 += BK) {
    float4 va = *(const float4*)(A + (size_t)(m0 + lrow) * K + k0 + lkq);
    As[lkq + 0][lrow] = va.x; As[lkq + 1][lrow] = va.y;
    As[lkq + 2][lrow] = va.z; As[lkq + 3][lrow] = va.w;
    float4 vb = make_float4(0.f, 0.f, 0.f, 0.f);
    if (n0 + lrow < N) vb = *(const float4*)(B + (size_t)(n0 + lrow) * K + k0 + lkq);
    Bs[lkq + 0][lrow] = vb.x; Bs[lkq + 1][lrow] = vb.y;
    Bs[lkq + 2][lrow] = vb.z; Bs[lkq + 3][lrow] = vb.w;
    __syncthreads();
#pragma unroll
    for (int kk = 0; kk < BK; ++kk) {
      float a[4], b[4];
#pragma unroll
      for (int i = 0; i < 4; ++i) a[i] = As[kk][tm * 4 + i];
#pragma unroll
      for (int j = 0; j < 4; ++j) b[j] = Bs[kk][tn * 4 + j];
#pragma unroll
      for (int i = 0; i < 4; ++i)
#pragma unroll
        for (int j = 0; j < 4; ++j) acc[i][j] += a[i] * b[j];
    }
    __syncthreads();
  }

#pragma unroll
  for (int i = 0; i < 4; ++i) {
    int m = m0 + tm * 4 + i;
    float bmv = 0.0f;
    if (bm1) bmv += bm1[m];
    if (bm2) bmv += bm2[m];
#pragma unroll
    for (int j = 0; j < 4; ++j) {
      int n = n0 + tn * 4 + j;
      if (n < N) {
        float v = acc[i][j] + bmv;
        if (bn) v += bn[n];
        C[(size_t)m * N + n] = v;
      }
    }
  }
}

// ---------------- persistent BiLSTM layer, batch-split: NO cross-block sync ---------
// Grid 4 blocks: blk>>1 = dir, blk&1 = batch half (16 of 32 n). 1024 threads = 16 waves.
// Each block holds the FULL W_hh (bf16 A-frags, 128 VGPR/lane) and iterates its 16
// batch elements through all 64 steps; h round-trips through double-buffered LDS only.
__global__ __launch_bounds__(1024, 4) void lstm_layer3(
    const float* __restrict__ xgT,   // [2][1024][2048]  (row, t*32+n)
    const float* __restrict__ Wfw,   // [1024][256]
    const float* __restrict__ Wbw,
    float* __restrict__ hcat) {      // [64][32][512]
  const int dir = blockIdx.x >> 1;
  const int nbase = (blockIdx.x & 1) * 16;
  const int tid = threadIdx.x;
  const int wid = tid >> 6;          // 0..15
  const int l = tid & 63;
  const int ln15 = l & 15;
  const int kg = l >> 4;             // 0..3
  const int u_wave = wid * 16;

  __shared__ unsigned short h_lds[2][16][256];  // [buf][n][k] bf16, XOR-swizzled 16B slots
  __shared__ float h_ex[2][256][17];            // [buf][unit][n]

  // ---- W_hh A-fragments into registers (once) ----
  const float* Wh = dir ? Wbw : Wfw;
  short8 afrag[4][8];
  {
    int gate = ln15 & 3, du = ln15 >> 2;
#pragma unroll
    for (int mt = 0; mt < 4; ++mt) {
      int row = gate * 256 + u_wave + mt * 4 + du;
      const float* wr = Wh + (size_t)row * 256;
#pragma unroll
      for (int kc = 0; kc < 8; ++kc) {
        short8 f;
#pragma unroll
        for (int j = 0; j < 8; ++j) f[j] = (short)bf16c(wr[kc * 32 + kg * 8 + j]);
        afrag[mt][kc] = f;
      }
    }
  }

  const float* xgd = xgT + (size_t)dir * (GROWS * 2048u);
  const int nglob = nbase + ln15;
  float cst[4] = {0.f, 0.f, 0.f, 0.f};
  f32x4 acc[4];

  // preload xg for step 0
  {
    int t0 = dir ? 63 : 0;
#pragma unroll
    for (int mt = 0; mt < 4; ++mt) {
      int unit = u_wave + mt * 4 + kg;
#pragma unroll
      for (int j = 0; j < 4; ++j)
        acc[mt][j] = xgd[((size_t)j * 256 + unit) * 2048 + t0 * NSEQ + nglob];
    }
  }

  const int my_swz = (ln15 & 7) << 4;   // read/write swizzle for row ln15

  for (int s = 0; s < TSTEPS; ++s) {
    const int t = dir ? (63 - s) : s;
    const int p = s & 1;

    // ---- MFMA: gates += W_hh * h_{t-1} (h in LDS buf p) ----
    if (s > 0) {
      const char* hrow = (const char*)&h_lds[p][ln15][0];
#pragma unroll
      for (int kc = 0; kc < 8; ++kc) {
        short8 b0 = *(const short8*)(hrow + ((kc * 64 + kg * 16) ^ my_swz));
#pragma unroll
        for (int mt = 0; mt < 4; ++mt)
          acc[mt] = __builtin_amdgcn_mfma_f32_16x16x32_bf16(afrag[mt][kc], b0, acc[mt], 0, 0, 0);
      }
    }

    // ---- LSTM cell (lane-local; c in registers) ----
#pragma unroll
    for (int mt = 0; mt < 4; ++mt) {
      int unit = u_wave + mt * 4 + kg;
      float gi = sigm(acc[mt][0]);
      float gf = sigm(acc[mt][1]);
      float gg = tanh_fast(acc[mt][2]);
      float go = sigm(acc[mt][3]);
      float c = gf * cst[mt] + gi * gg;
      cst[mt] = c;
      float h = go * tanh_fast(c);
      // next-step MFMA operand (buf p^1), swizzled
      char* hrow = (char*)&h_lds[p ^ 1][ln15][0];
      *(unsigned short*)(hrow + ((unit * 2) ^ my_swz)) = bf16c(h);
      h_ex[p ^ 1][unit][ln15] = h;
    }

    // ---- prefetch next-step xg into acc (consumed after barrier) ----
    if (s < TSTEPS - 1) {
      int tn = dir ? (62 - s) : (s + 1);
#pragma unroll
      for (int mt = 0; mt < 4; ++mt) {
        int unit = u_wave + mt * 4 + kg;
#pragma unroll
        for (int j = 0; j < 4; ++j)
          acc[mt][j] = xgd[((size_t)j * 256 + unit) * 2048 + tn * NSEQ + nglob];
      }
    }

    __syncthreads();

    // ---- coalesced hcat write (1 KiB contiguous per n-row) ----
    {
      int n_loc = tid >> 6;            // 0..15
      int u4 = (tid & 63) * 4;         // 0..252
      float4 v;
      v.x = h_ex[p ^ 1][u4 + 0][n_loc];
      v.y = h_ex[p ^ 1][u4 + 1][n_loc];
      v.z = h_ex[p ^ 1][u4 + 2][n_loc];
      v.w = h_ex[p ^ 1][u4 + 3][n_loc];
      *(float4*)(hcat + ((size_t)t * NSEQ + nbase + n_loc) * 512 + dir * 256 + u4) = v;
    }
  }
}

// ---------------- fused log-softmax + CTC loss ----------------
#define CTC_S 17
__global__ __launch_bounds__(576) void ctc_kernel(
    const float* __restrict__ preds,   // [64][32][12]
    const int* __restrict__ text,      // [256]
    const int* __restrict__ text_len,  // [32]
    float* __restrict__ out) {
  __shared__ float alpha[NSEQ][CTC_S];
  __shared__ float nalpha[NSEQ][CTC_S];
  __shared__ float lse[NSEQ];
  __shared__ int ext[NSEQ][CTC_S];
  __shared__ unsigned char allow[NSEQ][CTC_S];
  __shared__ unsigned char validm[NSEQ][CTC_S];
  __shared__ int tlsh[NSEQ];
  __shared__ float logp_sh[NSEQ];

  int tid = threadIdx.x;
  int b = tid & 31, sIdx = tid >> 5;
  bool active = sIdx < CTC_S;

  if (tid < NSEQ) tlsh[tid] = text_len[tid];
  __syncthreads();

  if (active) {
    int tl = tlsh[b];
    int off = 0;
    for (int i = 0; i < b; ++i) off += tlsh[i];
    int e = 0;
    if (sIdx & 1) {
      int lbl = (sIdx - 1) >> 1;
      int idx = off + lbl;
      if (idx > 255) idx = 255;
      e = (lbl < tl) ? text[idx] : 0;
    }
    ext[b][sIdx] = e;
    validm[b][sIdx] = (sIdx < 2 * tl + 1) ? 1 : 0;
  }
  __syncthreads();
  if (active) {
    int e = ext[b][sIdx];
    bool same2 = (sIdx >= 2) && (e == ext[b][sIdx - 2]);
    allow[b][sIdx] = ((sIdx >= 2) && (e != 0) && !same2) ? 1 : 0;
  }
  if (tid < NSEQ) {
    const float* p = preds + (size_t)b * 12;
    float mx = p[0];
    for (int k = 1; k < 12; ++k) mx = fmaxf(mx, p[k]);
    float ssum = 0.f;
    for (int k = 0; k < 12; ++k) ssum += expf(p[k] - mx);
    lse[b] = mx + logf(ssum);
  }
  __syncthreads();
  if (active) {
    float a = -1e30f;
    if (sIdx == 0) a = preds[(size_t)b * 12 + 0] - lse[b];
    else if (sIdx == 1 && tlsh[b] > 0) a = preds[(size_t)b * 12 + ext[b][1]] - lse[b];
    alpha[b][sIdx] = a;
  }
  __syncthreads();

  for (int t = 1; t < TSTEPS; ++t) {
    if (tid < NSEQ) {
      const float* p = preds + ((size_t)t * NSEQ + b) * 12;
      float mx = p[0];
      for (int k = 1; k < 12; ++k) mx = fmaxf(mx, p[k]);
      float ssum = 0.f;
      for (int k = 0; k < 12; ++k) ssum += expf(p[k] - mx);
      lse[b] = mx + logf(ssum);
    }
    __syncthreads();
    if (active) {
      float a = alpha[b][sIdx];
      float a1 = (sIdx >= 1) ? alpha[b][sIdx - 1] : -1e30f;
      float a2 = (sIdx >= 2 && allow[b][sIdx]) ? alpha[b][sIdx - 2] : -1e30f;
      float m = fmaxf(a, fmaxf(a1, a2));
      float ssum = expf(a - m) + expf(a1 - m) + expf(a2 - m);
      float emit = preds[((size_t)t * NSEQ + b) * 12 + ext[b][sIdx]] - lse[b];
      float nv = m + logf(ssum) + emit;
      nalpha[b][sIdx] = validm[b][sIdx] ? nv : -1e30f;
    }
    __syncthreads();
    if (active) alpha[b][sIdx] = nalpha[b][sIdx];
    __syncthreads();
  }

  if (tid < NSEQ) {
    int tl = tlsh[b];
    float a1 = alpha[b][2 * tl];
    float a2 = (tl > 0) ? alpha[b][2 * tl - 1] : -1e30f;
    float m = fmaxf(a1, a2);
    logp_sh[b] = m + logf(expf(a1 - m) + expf(a2 - m));
  }
  __syncthreads();
  if (tid == 0) {
    float ssum = 0.f;
    for (int i = 0; i < NSEQ; ++i) ssum += logp_sh[i];
    out[0] = -ssum / (float)NSEQ;
  }
}

// ---------------- launch ----------------
extern "C" void kernel_launch(void* const* d_in, const int* in_sizes, int n_in,
                              void* d_out, int out_size, void* d_ws, size_t ws_size,
                              hipStream_t stream) {
  (void)in_sizes; (void)n_in; (void)out_size; (void)ws_size;
  const float* base_feat = (const float*)d_in[0];
  const int* text = (const int*)d_in[1];
  const int* text_len = (const int*)d_in[2];
  const float* rois = (const float*)d_in[3];
  const float* l1_fw_W_ih = (const float*)d_in[4];
  const float* l1_fw_W_hh = (const float*)d_in[5];
  const float* l1_fw_b_ih = (const float*)d_in[6];
  const float* l1_fw_b_hh = (const float*)d_in[7];
  const float* l1_bw_W_ih = (const float*)d_in[8];
  const float* l1_bw_W_hh = (const float*)d_in[9];
  const float* l1_bw_b_ih = (const float*)d_in[10];
  const float* l1_bw_b_hh = (const float*)d_in[11];
  const float* l2_fw_W_ih = (const float*)d_in[12];
  const float* l2_fw_W_hh = (const float*)d_in[13];
  const float* l2_fw_b_ih = (const float*)d_in[14];
  const float* l2_fw_b_hh = (const float*)d_in[15];
  const float* l2_bw_W_ih = (const float*)d_in[16];
  const float* l2_bw_W_hh = (const float*)d_in[17];
  const float* l2_bw_b_ih = (const float*)d_in[18];
  const float* l2_bw_b_hh = (const float*)d_in[19];
  const float* W_emb1 = (const float*)d_in[20];
  const float* b_emb1 = (const float*)d_in[21];
  const float* W_emb2 = (const float*)d_in[22];
  const float* b_emb2 = (const float*)d_in[23];

  float* ws = (float*)d_ws;
  float* xg    = ws + OFF_XG;
  unsigned short* rnnb = (unsigned short*)(ws + OFF_RNNB);
  unsigned short* w1fb = (unsigned short*)(ws + OFF_W1FB);
  unsigned short* w1bb = (unsigned short*)(ws + OFF_W1BB);
  float* hcat1 = ws + OFF_HCAT1;
  float* h1    = ws + OFF_H1;
  float* hcat2 = ws + OFF_HCAT2;
  float* preds = ws + OFF_PREDS;

  // 0) W_ih layer-1 -> bf16 (1024x1024 each)
  cvt_bf16<<<1024, 256, 0, stream>>>(l1_fw_W_ih, w1fb, 262144);
  cvt_bf16<<<1024, 256, 0, stream>>>(l1_bw_W_ih, w1bb, 262144);

  // 1) ROI max pool -> rnn bf16 [2048][1024]
  roi_pool_kernel<<<dim3(32, 256), 256, 0, stream>>>(base_feat, rois, rnnb);

  // 2) xg layer1 via bf16 MFMA GEMM: [1024][2048] per dir
  gemm_bf16<<<dim3(16, 8), 256, 0, stream>>>(w1fb, rnnb, xg,
      1024, 2048, 1024, l1_fw_b_ih, l1_fw_b_hh);
  gemm_bf16<<<dim3(16, 8), 256, 0, stream>>>(w1bb, rnnb, xg + 2097152u,
      1024, 2048, 1024, l1_bw_b_ih, l1_bw_b_hh);

  // 3) layer-1 recurrence: 4 independent blocks (dir x batch-half), no global sync
  lstm_layer3<<<4, 1024, 0, stream>>>(xg, l1_fw_W_hh, l1_bw_W_hh, hcat1);

  // 4) h1 = hcat1 @ W_emb1^T + b_emb1
  gemm_nt<<<dim3(4, 32), 256, 0, stream>>>(hcat1, W_emb1, h1,
      2048, 256, 512, nullptr, nullptr, b_emb1);

  // 5) xg layer2 (f32 scalar; K=256)
  gemm_nt<<<dim3(32, 16), 256, 0, stream>>>(l2_fw_W_ih, h1, xg,
      1024, 2048, 256, l2_fw_b_ih, l2_fw_b_hh, nullptr);
  gemm_nt<<<dim3(32, 16), 256, 0, stream>>>(l2_bw_W_ih, h1, xg + 2097152u,
      1024, 2048, 256, l2_bw_b_ih, l2_bw_b_hh, nullptr);

  // 6) layer-2 recurrence
  lstm_layer3<<<4, 1024, 0, stream>>>(xg, l2_fw_W_hh, l2_bw_W_hh, hcat2);

  // 7) preds = hcat2 @ W_emb2^T + b_emb2
  gemm_nt<<<dim3(1, 32), 256, 0, stream>>>(hcat2, W_emb2, preds,
      2048, 12, 512, nullptr, nullptr, b_emb2);

  // 8) log-softmax + CTC
  ctc_kernel<<<1, 576, 0, stream>>>(preds, text, text_len, (float*)d_out);
}

// Round 5
// 1190.760 us; speedup vs baseline: 1.6875x; 1.6875x over previous
//
#include <hip/hip_runtime.h>
#include <math.h>

// ---------------- problem constants ----------------
#define TSTEPS 64
#define NSEQ   32
#define HID    256
#define GROWS  1024
#define FH     40
#define FW     160

// ---------------- workspace layout (float units) ----------------
#define OFF_XG     0u            // [2][2048][1024] f32, interleaved (tn, unit*4+gate)
#define OFF_RNNB   4194304u      // [2048][1024] bf16
#define OFF_W1FB   5242880u      // l1 fw W_ih bf16 1024x1024
#define OFF_W1BB   5767168u
#define OFF_W2FB   6291456u      // l2 fw W_ih bf16 1024x256
#define OFF_W2BB   6422528u
#define OFF_WE1B   6553600u      // W_emb1 bf16 256x512
#define OFF_WE2B   6619136u      // W_emb2 bf16 12x512 (3072 floats)
#define OFF_HCB1   6622208u      // hcat1 bf16 [2048][512]
#define OFF_HCB2   7146496u      // hcat2 bf16
#define OFF_H1B    7670784u      // h1 bf16 [2048][256]
#define OFF_PREDS  7932928u      // [2048][12] f32

typedef __attribute__((ext_vector_type(8))) short short8;
typedef __attribute__((ext_vector_type(4))) float f32x4;
typedef __attribute__((ext_vector_type(4))) unsigned short ushort4v;

static __device__ inline unsigned short bf16c(float x) {
  union { float f; unsigned u; } v; v.f = x;
  unsigned r = v.u + 0x7fff + ((v.u >> 16) & 1);   // RNE
  return (unsigned short)(r >> 16);
}

static __device__ inline float sigm(float x) {
  return __builtin_amdgcn_rcpf(1.0f + __expf(-x));
}
static __device__ inline float tanh_fast(float x) {
  return 1.0f - 2.0f * __builtin_amdgcn_rcpf(1.0f + __expf(2.0f * x));
}

// ---------------- f32 -> bf16 converter ----------------
__global__ __launch_bounds__(256) void cvt_bf16(
    const float* __restrict__ in, unsigned short* __restrict__ out, int n4) {
  int i = blockIdx.x * 256 + threadIdx.x;
  if (i < n4) {
    float4 v = ((const float4*)in)[i];
    ushort4v o;
    o[0] = bf16c(v.x); o[1] = bf16c(v.y); o[2] = bf16c(v.z); o[3] = bf16c(v.w);
    ((ushort4v*)out)[i] = o;
  }
}

// ---------------- ROI max pool -> rnn bf16 [t*32+n][c*2+ph] ----------------
__global__ __launch_bounds__(256) void roi_pool_kernel(
    const float* __restrict__ feat, const float* __restrict__ rois,
    unsigned short* __restrict__ rnn) {
  int n  = blockIdx.x;
  int cg = blockIdx.y;
  int tid = threadIdx.x;
  int pw = tid & 63, ph = (tid >> 6) & 1, cl = tid >> 7;
  int c = cg * 2 + cl;

  const float* r = rois + n * 5;
  int bi = (int)r[0];
  int x1 = (int)rintf(r[1] * (float)FW);
  int y1 = (int)rintf(r[2] * (float)FH);
  int x2 = (int)rintf(r[3] * (float)FW);
  int y2 = (int)rintf(r[4] * (float)FH);
  float rw = fmaxf((float)(x2 - x1 + 1), 1.0f);
  float rh = fmaxf((float)(y2 - y1 + 1), 1.0f);
  float bin_h = rh * 0.5f;
  float bin_w = rw * (1.0f / 64.0f);

  int hs = min(max((int)floorf((float)ph * bin_h) + y1, 0), FH);
  int he = min(max((int)ceilf((float)(ph + 1) * bin_h) + y1, 0), FH);
  int wst = min(max((int)floorf((float)pw * bin_w) + x1, 0), FW);
  int wen = min(max((int)ceilf((float)(pw + 1) * bin_w) + x1, 0), FW);

  float m = -1e30f;
  bool nonempty = (hs < he) && (wst < wen);
  const float* f = feat + ((size_t)bi * 512 + c) * (FH * FW);
  for (int h = hs; h < he; ++h) {
    const float* fr = f + h * FW;
    for (int w = wst; w < wen; ++w) m = fmaxf(m, fr[w]);
  }
  float out = nonempty ? m : 0.0f;
  rnn[((size_t)pw * NSEQ + n) * 1024 + c * 2 + ph] = bf16c(out);
}

// ---------------- bf16 MFMA GEMM ----------------
// C[M][N] (+bias) = A[M,K]bf16 @ B[N,K]bf16^T. 128x128 tile, BK=32, 256 thr.
// mode 0: Cf[m*N+n] f32; mode 1: Cb[m*N+n] bf16; mode 2: Cf[n*1024+(m&255)*4+(m>>8)]
#define GPITCH 40
__global__ __launch_bounds__(256) void gemm_bf16(
    const unsigned short* __restrict__ A, const unsigned short* __restrict__ B,
    float* __restrict__ Cf, unsigned short* __restrict__ Cb,
    int M, int N, int K,
    const float* __restrict__ bm1, const float* __restrict__ bm2,
    const float* __restrict__ bn, int mode) {
  __shared__ unsigned short Al[128 * GPITCH];
  __shared__ unsigned short Bl[128 * GPITCH];
  int m0 = blockIdx.y * 128, n0 = blockIdx.x * 128;
  int tid = threadIdx.x;
  int wid = tid >> 6, l = tid & 63, ln15 = l & 15, kg = l >> 4;
  int wm = wid >> 1, wn = wid & 1;

  f32x4 acc[4][4];
#pragma unroll
  for (int i = 0; i < 4; ++i)
#pragma unroll
    for (int j = 0; j < 4; ++j)
#pragma unroll
      for (int q = 0; q < 4; ++q) acc[i][j][q] = 0.0f;

  for (int k0 = 0; k0 < K; k0 += 32) {
#pragma unroll
    for (int it = 0; it < 2; ++it) {
      int chunk = tid + it * 256;
      int row = chunk >> 2, part = chunk & 3;
      short8 va = *(const short8*)(A + (size_t)(m0 + row) * K + k0 + part * 8);
      *(short8*)(Al + row * GPITCH + part * 8) = va;
      short8 vb;
      if (n0 + row < N) {
        vb = *(const short8*)(B + (size_t)(n0 + row) * K + k0 + part * 8);
      } else {
#pragma unroll
        for (int q = 0; q < 8; ++q) vb[q] = 0;
      }
      *(short8*)(Bl + row * GPITCH + part * 8) = vb;
    }
    __syncthreads();

    short8 a[4], b[4];
#pragma unroll
    for (int mt = 0; mt < 4; ++mt)
      a[mt] = *(const short8*)(Al + (wm * 64 + mt * 16 + ln15) * GPITCH + kg * 8);
#pragma unroll
    for (int nt = 0; nt < 4; ++nt)
      b[nt] = *(const short8*)(Bl + (wn * 64 + nt * 16 + ln15) * GPITCH + kg * 8);
#pragma unroll
    for (int mt = 0; mt < 4; ++mt)
#pragma unroll
      for (int nt = 0; nt < 4; ++nt)
        acc[mt][nt] = __builtin_amdgcn_mfma_f32_16x16x32_bf16(a[mt], b[nt], acc[mt][nt], 0, 0, 0);
    __syncthreads();
  }

#pragma unroll
  for (int mt = 0; mt < 4; ++mt) {
#pragma unroll
    for (int j = 0; j < 4; ++j) {
      int m = m0 + wm * 64 + mt * 16 + kg * 4 + j;
      float bmv = 0.0f;
      if (bm1) bmv += bm1[m];
      if (bm2) bmv += bm2[m];
#pragma unroll
      for (int nt = 0; nt < 4; ++nt) {
        int n = n0 + wn * 64 + nt * 16 + ln15;
        float v = acc[mt][nt][j] + bmv;
        if (bn && n < N) v += bn[n];
        if (mode == 2) {
          Cf[(size_t)n * 1024 + (m & 255) * 4 + (m >> 8)] = v;
        } else if (n < N) {
          if (mode == 1) Cb[(size_t)m * N + n] = bf16c(v);
          else Cf[(size_t)m * N + n] = v;
        }
      }
    }
  }
}

// ---------------- persistent BiLSTM layer, batch-split, reg+LDS weights --------
// Grid 4 blocks: dir = blk>>1, batch-half = blk&1 (16 n each). 512 thr = 8 waves.
// Per wave: 8 m-tiles (32 units x 4 gates, gate-interleaved rows). Tiles 0-5 in
// registers (192 VGPR), tiles 6-7 in LDS (16KB/wave). No cross-block sync.
__global__ __launch_bounds__(512, 2) void lstm_layer4(
    const float* __restrict__ xg,    // [2][2048][1024] interleaved (tn, unit*4+gate)
    const float* __restrict__ Wfw,   // [1024][256] f32
    const float* __restrict__ Wbw,
    unsigned short* __restrict__ hcatb) {  // [64][32][512] bf16
  const int dir = blockIdx.x >> 1;
  const int nbase = (blockIdx.x & 1) * 16;
  const int tid = threadIdx.x;
  const int w = tid >> 6;
  const int l = tid & 63;
  const int ln15 = l & 15;
  const int kg = l >> 4;
  const int u_wave = w * 32;

  __shared__ unsigned short h_lds[2][16][256];     // 16KB, XOR-swizzled 16B slots
  __shared__ unsigned short wt[8][2][16][256];     // 128KB [wave][tt][row][k], swizzled

  const float* Wh = dir ? Wbw : Wfw;
  const int swz = (ln15 & 7) << 4;

  // ---- LDS weight tiles (mt 6,7): each wave fills its own ----
#pragma unroll
  for (int tt = 0; tt < 2; ++tt) {
    int mt = 6 + tt;
    for (int q = 0; q < 8; ++q) {
      int flat = q * 64 + l;
      int r = flat >> 5, slot = flat & 31;
      int gate = r & 3, du = r >> 2;
      const float* src = Wh + (size_t)(gate * 256 + u_wave + mt * 4 + du) * 256 + slot * 8;
      short8 f;
#pragma unroll
      for (int j = 0; j < 8; ++j) f[j] = (short)bf16c(src[j]);
      *(short8*)((char*)&wt[w][tt][0][0] + r * 512 + ((slot * 16) ^ ((r & 7) << 4))) = f;
    }
  }

  // ---- register weight tiles (mt 0..5) ----
  short8 afrag[6][8];
  {
    int gate = ln15 & 3, du = ln15 >> 2;
#pragma unroll
    for (int mt = 0; mt < 6; ++mt) {
      const float* wr = Wh + (size_t)(gate * 256 + u_wave + mt * 4 + du) * 256;
#pragma unroll
      for (int kc = 0; kc < 8; ++kc) {
        short8 f;
#pragma unroll
        for (int j = 0; j < 8; ++j) f[j] = (short)bf16c(wr[kc * 32 + kg * 8 + j]);
        afrag[mt][kc] = f;
      }
    }
  }

  const float* xgd = xg + (size_t)dir * 2097152u;
  float cst[8] = {0.f, 0.f, 0.f, 0.f, 0.f, 0.f, 0.f, 0.f};
  f32x4 acc[8];

  {
    int t0 = dir ? 63 : 0;
    const float* xb = xgd + (size_t)(t0 * 32 + nbase + ln15) * 1024 + (u_wave + kg) * 4;
#pragma unroll
    for (int mt = 0; mt < 8; ++mt) acc[mt] = *(const f32x4*)(xb + mt * 16);
  }

  for (int s = 0; s < TSTEPS; ++s) {
    const int t = dir ? (63 - s) : s;

    if (s > 0) {
      const char* hrow = (const char*)&h_lds[s & 1][ln15][0];
      const char* w6 = (const char*)&wt[w][0][0][0] + ln15 * 512;
      const char* w7 = (const char*)&wt[w][1][0][0] + ln15 * 512;
#pragma unroll
      for (int kc = 0; kc < 8; ++kc) {
        int off = (kg * 16 + kc * 64) ^ swz;
        short8 b = *(const short8*)(hrow + off);
        short8 a6 = *(const short8*)(w6 + off);
        short8 a7 = *(const short8*)(w7 + off);
#pragma unroll
        for (int mt = 0; mt < 6; ++mt)
          acc[mt] = __builtin_amdgcn_mfma_f32_16x16x32_bf16(afrag[mt][kc], b, acc[mt], 0, 0, 0);
        acc[6] = __builtin_amdgcn_mfma_f32_16x16x32_bf16(a6, b, acc[6], 0, 0, 0);
        acc[7] = __builtin_amdgcn_mfma_f32_16x16x32_bf16(a7, b, acc[7], 0, 0, 0);
      }
    }

    // ---- LSTM cell: acc j = gate j of unit (u_wave + mt*4 + kg), n = nbase+ln15 ----
    {
      char* hw = (char*)&h_lds[(s + 1) & 1][ln15][0];
#pragma unroll
      for (int mt = 0; mt < 8; ++mt) {
        float gi = sigm(acc[mt][0]);
        float gf = sigm(acc[mt][1]);
        float gg = tanh_fast(acc[mt][2]);
        float go = sigm(acc[mt][3]);
        float c = gf * cst[mt] + gi * gg;
        cst[mt] = c;
        float h = go * tanh_fast(c);
        int unit = u_wave + mt * 4 + kg;
        *(unsigned short*)(hw + ((unit * 2) ^ swz)) = bf16c(h);
      }
    }

    // ---- prefetch next-step xg into acc ----
    if (s < TSTEPS - 1) {
      int tn = dir ? (t - 1) : (t + 1);
      const float* xb = xgd + (size_t)(tn * 32 + nbase + ln15) * 1024 + (u_wave + kg) * 4;
#pragma unroll
      for (int mt = 0; mt < 8; ++mt) acc[mt] = *(const f32x4*)(xb + mt * 16);
    }

    __syncthreads();

    // ---- hcat write (bf16, from the just-written buffer) ----
    {
      int n_loc = tid >> 5;
      int u0 = (tid & 31) * 8;
      const char* src = (const char*)&h_lds[(s + 1) & 1][n_loc][0];
      short8 v = *(const short8*)(src + ((u0 * 2) ^ ((n_loc & 7) << 4)));
      *(short8*)(hcatb + ((size_t)t * NSEQ + nbase + n_loc) * 512 + dir * 256 + u0) = v;
    }
  }
}

// ---------------- fused log-softmax + CTC loss ----------------
#define CTC_S 17
__global__ __launch_bounds__(576) void ctc_kernel(
    const float* __restrict__ preds,   // [64][32][12]
    const int* __restrict__ text,      // [256]
    const int* __restrict__ text_len,  // [32]
    float* __restrict__ out) {
  __shared__ float alpha[NSEQ][CTC_S];
  __shared__ float nalpha[NSEQ][CTC_S];
  __shared__ float lse[NSEQ];
  __shared__ int ext[NSEQ][CTC_S];
  __shared__ unsigned char allow[NSEQ][CTC_S];
  __shared__ unsigned char validm[NSEQ][CTC_S];
  __shared__ int tlsh[NSEQ];
  __shared__ float logp_sh[NSEQ];

  int tid = threadIdx.x;
  int b = tid & 31, sIdx = tid >> 5;
  bool active = sIdx < CTC_S;

  if (tid < NSEQ) tlsh[tid] = text_len[tid];
  __syncthreads();

  if (active) {
    int tl = tlsh[b];
    int off = 0;
    for (int i = 0; i < b; ++i) off += tlsh[i];
    int e = 0;
    if (sIdx & 1) {
      int lbl = (sIdx - 1) >> 1;
      int idx = off + lbl;
      if (idx > 255) idx = 255;
      e = (lbl < tl) ? text[idx] : 0;
    }
    ext[b][sIdx] = e;
    validm[b][sIdx] = (sIdx < 2 * tl + 1) ? 1 : 0;
  }
  __syncthreads();
  if (active) {
    int e = ext[b][sIdx];
    bool same2 = (sIdx >= 2) && (e == ext[b][sIdx - 2]);
    allow[b][sIdx] = ((sIdx >= 2) && (e != 0) && !same2) ? 1 : 0;
  }
  if (tid < NSEQ) {
    const float* p = preds + (size_t)b * 12;
    float mx = p[0];
    for (int k = 1; k < 12; ++k) mx = fmaxf(mx, p[k]);
    float ssum = 0.f;
    for (int k = 0; k < 12; ++k) ssum += expf(p[k] - mx);
    lse[b] = mx + logf(ssum);
  }
  __syncthreads();
  if (active) {
    float a = -1e30f;
    if (sIdx == 0) a = preds[(size_t)b * 12 + 0] - lse[b];
    else if (sIdx == 1 && tlsh[b] > 0) a = preds[(size_t)b * 12 + ext[b][1]] - lse[b];
    alpha[b][sIdx] = a;
  }
  __syncthreads();

  for (int t = 1; t < TSTEPS; ++t) {
    if (tid < NSEQ) {
      const float* p = preds + ((size_t)t * NSEQ + b) * 12;
      float mx = p[0];
      for (int k = 1; k < 12; ++k) mx = fmaxf(mx, p[k]);
      float ssum = 0.f;
      for (int k = 0; k < 12; ++k) ssum += expf(p[k] - mx);
      lse[b] = mx + logf(ssum);
    }
    __syncthreads();
    if (active) {
      float a = alpha[b][sIdx];
      float a1 = (sIdx >= 1) ? alpha[b][sIdx - 1] : -1e30f;
      float a2 = (sIdx >= 2 && allow[b][sIdx]) ? alpha[b][sIdx - 2] : -1e30f;
      float m = fmaxf(a, fmaxf(a1, a2));
      float ssum = expf(a - m) + expf(a1 - m) + expf(a2 - m);
      float emit = preds[((size_t)t * NSEQ + b) * 12 + ext[b][sIdx]] - lse[b];
      float nv = m + logf(ssum) + emit;
      nalpha[b][sIdx] = validm[b][sIdx] ? nv : -1e30f;
    }
    __syncthreads();
    if (active) alpha[b][sIdx] = nalpha[b][sIdx];
    __syncthreads();
  }

  if (tid < NSEQ) {
    int tl = tlsh[b];
    float a1 = alpha[b][2 * tl];
    float a2 = (tl > 0) ? alpha[b][2 * tl - 1] : -1e30f;
    float m = fmaxf(a1, a2);
    logp_sh[b] = m + logf(expf(a1 - m) + expf(a2 - m));
  }
  __syncthreads();
  if (tid == 0) {
    float ssum = 0.f;
    for (int i = 0; i < NSEQ; ++i) ssum += logp_sh[i];
    out[0] = -ssum / (float)NSEQ;
  }
}

// ---------------- launch ----------------
extern "C" void kernel_launch(void* const* d_in, const int* in_sizes, int n_in,
                              void* d_out, int out_size, void* d_ws, size_t ws_size,
                              hipStream_t stream) {
  (void)in_sizes; (void)n_in; (void)out_size; (void)ws_size;
  const float* base_feat = (const float*)d_in[0];
  const int* text = (const int*)d_in[1];
  const int* text_len = (const int*)d_in[2];
  const float* rois = (const float*)d_in[3];
  const float* l1_fw_W_ih = (const float*)d_in[4];
  const float* l1_fw_W_hh = (const float*)d_in[5];
  const float* l1_fw_b_ih = (const float*)d_in[6];
  const float* l1_fw_b_hh = (const float*)d_in[7];
  const float* l1_bw_W_ih = (const float*)d_in[8];
  const float* l1_bw_W_hh = (const float*)d_in[9];
  const float* l1_bw_b_ih = (const float*)d_in[10];
  const float* l1_bw_b_hh = (const float*)d_in[11];
  const float* l2_fw_W_ih = (const float*)d_in[12];
  const float* l2_fw_W_hh = (const float*)d_in[13];
  const float* l2_fw_b_ih = (const float*)d_in[14];
  const float* l2_fw_b_hh = (const float*)d_in[15];
  const float* l2_bw_W_ih = (const float*)d_in[16];
  const float* l2_bw_W_hh = (const float*)d_in[17];
  const float* l2_bw_b_ih = (const float*)d_in[18];
  const float* l2_bw_b_hh = (const float*)d_in[19];
  const float* W_emb1 = (const float*)d_in[20];
  const float* b_emb1 = (const float*)d_in[21];
  const float* W_emb2 = (const float*)d_in[22];
  const float* b_emb2 = (const float*)d_in[23];

  float* ws = (float*)d_ws;
  float* xg = ws + OFF_XG;
  unsigned short* rnnb  = (unsigned short*)(ws + OFF_RNNB);
  unsigned short* w1fb  = (unsigned short*)(ws + OFF_W1FB);
  unsigned short* w1bb  = (unsigned short*)(ws + OFF_W1BB);
  unsigned short* w2fb  = (unsigned short*)(ws + OFF_W2FB);
  unsigned short* w2bb  = (unsigned short*)(ws + OFF_W2BB);
  unsigned short* we1b  = (unsigned short*)(ws + OFF_WE1B);
  unsigned short* we2b  = (unsigned short*)(ws + OFF_WE2B);
  unsigned short* hcb1  = (unsigned short*)(ws + OFF_HCB1);
  unsigned short* hcb2  = (unsigned short*)(ws + OFF_HCB2);
  unsigned short* h1b   = (unsigned short*)(ws + OFF_H1B);
  float* preds = ws + OFF_PREDS;

  // 0) weight conversions to bf16
  cvt_bf16<<<1024, 256, 0, stream>>>(l1_fw_W_ih, w1fb, 262144);
  cvt_bf16<<<1024, 256, 0, stream>>>(l1_bw_W_ih, w1bb, 262144);
  cvt_bf16<<<256, 256, 0, stream>>>(l2_fw_W_ih, w2fb, 65536);
  cvt_bf16<<<256, 256, 0, stream>>>(l2_bw_W_ih, w2bb, 65536);
  cvt_bf16<<<128, 256, 0, stream>>>(W_emb1, we1b, 32768);
  cvt_bf16<<<6, 256, 0, stream>>>(W_emb2, we2b, 1536);

  // 1) ROI max pool -> rnn bf16 [2048][1024]
  roi_pool_kernel<<<dim3(32, 256), 256, 0, stream>>>(base_feat, rois, rnnb);

  // 2) xg layer1 (mode 2: interleaved [tn][unit*4+gate])
  gemm_bf16<<<dim3(16, 8), 256, 0, stream>>>(w1fb, rnnb, xg, nullptr,
      1024, 2048, 1024, l1_fw_b_ih, l1_fw_b_hh, nullptr, 2);
  gemm_bf16<<<dim3(16, 8), 256, 0, stream>>>(w1bb, rnnb, xg + 2097152u, nullptr,
      1024, 2048, 1024, l1_bw_b_ih, l1_bw_b_hh, nullptr, 2);

  // 3) layer-1 recurrence (4 independent blocks, no global sync)
  lstm_layer4<<<4, 512, 0, stream>>>(xg, l1_fw_W_hh, l1_bw_W_hh, hcb1);

  // 4) h1 = hcat1 @ W_emb1^T + b_emb1 -> bf16 (mode 1)
  gemm_bf16<<<dim3(2, 16), 256, 0, stream>>>(hcb1, we1b, nullptr, h1b,
      2048, 256, 512, nullptr, nullptr, b_emb1, 1);

  // 5) xg layer2 (mode 2)
  gemm_bf16<<<dim3(16, 8), 256, 0, stream>>>(w2fb, h1b, xg, nullptr,
      1024, 2048, 256, l2_fw_b_ih, l2_fw_b_hh, nullptr, 2);
  gemm_bf16<<<dim3(16, 8), 256, 0, stream>>>(w2bb, h1b, xg + 2097152u, nullptr,
      1024, 2048, 256, l2_bw_b_ih, l2_bw_b_hh, nullptr, 2);

  // 6) layer-2 recurrence
  lstm_layer4<<<4, 512, 0, stream>>>(xg, l2_fw_W_hh, l2_bw_W_hh, hcb2);

  // 7) preds = hcat2 @ W_emb2^T + b_emb2 (mode 0, N=12 with guards)
  gemm_bf16<<<dim3(1, 16), 256, 0, stream>>>(hcb2, we2b, preds, nullptr,
      2048, 12, 512, nullptr, nullptr, b_emb2, 0);

  // 8) log-softmax + CTC
  ctc_kernel<<<1, 576, 0, stream>>>(preds, text, text_len, (float*)d_out);
}

// Round 6
// 916.745 us; speedup vs baseline: 2.1919x; 1.2989x over previous
//
#include <hip/hip_runtime.h>
#include <math.h>

// ---------------- problem constants ----------------
#define TSTEPS 64
#define NSEQ   32
#define FH     40
#define FW     160

// ---------------- workspace layout (float units) ----------------
#define OFF_XGB    0u            // [2][2048][1024] bf16 interleaved (tn, unit*4+gate)
#define OFF_RNNB   2097152u      // [2048][1024] bf16
#define OFF_W1FB   3145728u      // l1 fw W_ih bf16 1024x1024
#define OFF_W1BB   3670016u
#define OFF_W2FB   4194304u      // l2 fw W_ih bf16 1024x256
#define OFF_W2BB   4325376u
#define OFF_WE1B   4456448u      // W_emb1 bf16 256x512
#define OFF_WE2B   4521984u      // W_emb2 bf16 12x512
#define OFF_W8L1F  4526080u      // l1 fw W_hh fp8 (x64) 1024x256
#define OFF_W8L1B  4591616u
#define OFF_W8L2F  4657152u
#define OFF_W8L2B  4722688u
#define OFF_HCB1   4788224u      // hcat1 bf16 [2048][512]
#define OFF_HCB2   5312512u
#define OFF_H1B    5836800u      // h1 bf16 [2048][256]
#define OFF_PREDS  6098944u      // [2048][12] f32

typedef __attribute__((ext_vector_type(8))) short short8;
typedef __attribute__((ext_vector_type(4))) float f32x4;
typedef __attribute__((ext_vector_type(4))) unsigned short ushort4v;

static __device__ inline unsigned short bf16c(float x) {
  union { float f; unsigned u; } v; v.f = x;
  unsigned r = v.u + 0x7fff + ((v.u >> 16) & 1);   // RNE
  return (unsigned short)(r >> 16);
}
static __device__ inline float b2f(unsigned short u) {
  union { unsigned u; float f; } v; v.u = ((unsigned)u) << 16;
  return v.f;
}
// f32 -> fp8 e4m3fn (OCP): RNE, saturate to 448, flush subnormals (<2^-6) to 0
static __device__ inline unsigned char fp8c(float x) {
  union { float f; unsigned u; } v; v.f = x;
  unsigned s = (v.u >> 24) & 0x80;
  float ax = fabsf(x);
  if (ax < 0.015625f) return (unsigned char)s;
  if (ax >= 448.0f) return (unsigned char)(s | 0x7e);
  unsigned e = (v.u >> 23) & 0xff;
  unsigned m = v.u & 0x7fffff;
  unsigned r = m + 0x7ffff + ((m >> 20) & 1);
  if (r >> 23) { e += 1; r = 0; }
  unsigned m3 = (r >> 20) & 7;
  int ee = (int)e - 127 + 7;
  if (ee > 15) return (unsigned char)(s | 0x7e);
  return (unsigned char)(s | (ee << 3) | m3);
}

static __device__ inline float sigm(float x) {
  return __builtin_amdgcn_rcpf(1.0f + __expf(-x));
}
static __device__ inline float tanh_fast(float x) {
  return 1.0f - 2.0f * __builtin_amdgcn_rcpf(1.0f + __expf(2.0f * x));
}

// ---------------- f32 -> bf16 converter ----------------
__global__ __launch_bounds__(256) void cvt_bf16(
    const float* __restrict__ in, unsigned short* __restrict__ out, int n4) {
  int i = blockIdx.x * 256 + threadIdx.x;
  if (i < n4) {
    float4 v = ((const float4*)in)[i];
    ushort4v o;
    o[0] = bf16c(v.x); o[1] = bf16c(v.y); o[2] = bf16c(v.z); o[3] = bf16c(v.w);
    ((ushort4v*)out)[i] = o;
  }
}

// ---------------- f32 -> fp8 (x64 scale) converter ----------------
__global__ __launch_bounds__(256) void cvt_fp8(
    const float* __restrict__ in, unsigned char* __restrict__ out, int n4) {
  int i = blockIdx.x * 256 + threadIdx.x;
  if (i < n4) {
    float4 v = ((const float4*)in)[i];
    unsigned o = (unsigned)fp8c(v.x * 64.0f)
               | ((unsigned)fp8c(v.y * 64.0f) << 8)
               | ((unsigned)fp8c(v.z * 64.0f) << 16)
               | ((unsigned)fp8c(v.w * 64.0f) << 24);
    ((unsigned*)out)[i] = o;
  }
}

// ---------------- ROI max pool -> rnn bf16 [t*32+n][c*2+ph] ----------------
__global__ __launch_bounds__(256) void roi_pool_kernel(
    const float* __restrict__ feat, const float* __restrict__ rois,
    unsigned short* __restrict__ rnn) {
  int n  = blockIdx.x;
  int cg = blockIdx.y;
  int tid = threadIdx.x;
  int pw = tid & 63, ph = (tid >> 6) & 1, cl = tid >> 7;
  int c = cg * 2 + cl;

  const float* r = rois + n * 5;
  int bi = (int)r[0];
  int x1 = (int)rintf(r[1] * (float)FW);
  int y1 = (int)rintf(r[2] * (float)FH);
  int x2 = (int)rintf(r[3] * (float)FW);
  int y2 = (int)rintf(r[4] * (float)FH);
  float rw = fmaxf((float)(x2 - x1 + 1), 1.0f);
  float rh = fmaxf((float)(y2 - y1 + 1), 1.0f);
  float bin_h = rh * 0.5f;
  float bin_w = rw * (1.0f / 64.0f);

  int hs = min(max((int)floorf((float)ph * bin_h) + y1, 0), FH);
  int he = min(max((int)ceilf((float)(ph + 1) * bin_h) + y1, 0), FH);
  int wst = min(max((int)floorf((float)pw * bin_w) + x1, 0), FW);
  int wen = min(max((int)ceilf((float)(pw + 1) * bin_w) + x1, 0), FW);

  float m = -1e30f;
  bool nonempty = (hs < he) && (wst < wen);
  const float* f = feat + ((size_t)bi * 512 + c) * (FH * FW);
  for (int h = hs; h < he; ++h) {
    const float* fr = f + h * FW;
    for (int w = wst; w < wen; ++w) m = fmaxf(m, fr[w]);
  }
  float out = nonempty ? m : 0.0f;
  rnn[((size_t)pw * NSEQ + n) * 1024 + c * 2 + ph] = bf16c(out);
}

// ---------------- bf16 MFMA GEMM ----------------
// C = A[M,K]bf16 @ B[N,K]bf16^T + bias(m) + bias(n). 128x128 tile, BK=32.
// mode 0: Cf[m*N+n] f32; mode 1: Cb[m*N+n] bf16;
// mode 3: Cb[n*1024 + (m&255)*4 + (m>>8)] bf16  (xg interleave, M=1024)
#define GPITCH 40
__global__ __launch_bounds__(256) void gemm_bf16(
    const unsigned short* __restrict__ A, const unsigned short* __restrict__ B,
    float* __restrict__ Cf, unsigned short* __restrict__ Cb,
    int M, int N, int K,
    const float* __restrict__ bm1, const float* __restrict__ bm2,
    const float* __restrict__ bn, int mode) {
  __shared__ unsigned short Al[128 * GPITCH];
  __shared__ unsigned short Bl[128 * GPITCH];
  int m0 = blockIdx.y * 128, n0 = blockIdx.x * 128;
  int tid = threadIdx.x;
  int wid = tid >> 6, l = tid & 63, ln15 = l & 15, kg = l >> 4;
  int wm = wid >> 1, wn = wid & 1;

  f32x4 acc[4][4];
#pragma unroll
  for (int i = 0; i < 4; ++i)
#pragma unroll
    for (int j = 0; j < 4; ++j)
#pragma unroll
      for (int q = 0; q < 4; ++q) acc[i][j][q] = 0.0f;

  for (int k0 = 0; k0 < K; k0 += 32) {
#pragma unroll
    for (int it = 0; it < 2; ++it) {
      int chunk = tid + it * 256;
      int row = chunk >> 2, part = chunk & 3;
      short8 va = *(const short8*)(A + (size_t)(m0 + row) * K + k0 + part * 8);
      *(short8*)(Al + row * GPITCH + part * 8) = va;
      short8 vb;
      if (n0 + row < N) {
        vb = *(const short8*)(B + (size_t)(n0 + row) * K + k0 + part * 8);
      } else {
#pragma unroll
        for (int q = 0; q < 8; ++q) vb[q] = 0;
      }
      *(short8*)(Bl + row * GPITCH + part * 8) = vb;
    }
    __syncthreads();

    short8 a[4], b[4];
#pragma unroll
    for (int mt = 0; mt < 4; ++mt)
      a[mt] = *(const short8*)(Al + (wm * 64 + mt * 16 + ln15) * GPITCH + kg * 8);
#pragma unroll
    for (int nt = 0; nt < 4; ++nt)
      b[nt] = *(const short8*)(Bl + (wn * 64 + nt * 16 + ln15) * GPITCH + kg * 8);
#pragma unroll
    for (int mt = 0; mt < 4; ++mt)
#pragma unroll
      for (int nt = 0; nt < 4; ++nt)
        acc[mt][nt] = __builtin_amdgcn_mfma_f32_16x16x32_bf16(a[mt], b[nt], acc[mt][nt], 0, 0, 0);
    __syncthreads();
  }

#pragma unroll
  for (int mt = 0; mt < 4; ++mt) {
#pragma unroll
    for (int j = 0; j < 4; ++j) {
      int m = m0 + wm * 64 + mt * 16 + kg * 4 + j;
      float bmv = 0.0f;
      if (bm1) bmv += bm1[m];
      if (bm2) bmv += bm2[m];
#pragma unroll
      for (int nt = 0; nt < 4; ++nt) {
        int n = n0 + wn * 64 + nt * 16 + ln15;
        float v = acc[mt][nt][j] + bmv;
        if (bn && n < N) v += bn[n];
        if (mode == 3) {
          Cb[(size_t)n * 1024 + (m & 255) * 4 + (m >> 8)] = bf16c(v);
        } else if (n < N) {
          if (mode == 1) Cb[(size_t)m * N + n] = bf16c(v);
          else Cf[(size_t)m * N + n] = v;
        }
      }
    }
  }
}

// ---------------- persistent BiLSTM layer: fp8 weights fully in registers -------
// Grid 4 blocks: dir = blk>>1, batch-half = blk&1 (n=16). 512 thr = 8 waves.
// Per wave: 8 m-tiles (32 units x 4 gates, gate-interleaved). afrag[8][8] fp8
// i64 frags = 128 VGPR/lane -> total demand ~200/wave, under the 256 cap: NO
// spill. h quantized to fp8 (x16) in swizzled LDS; W scaled x64; acc carries
// 1024x (init = 1024*xg, cell scales by 1/1024). No cross-block sync.
__global__ __launch_bounds__(512, 2) void lstm_layer5(
    const unsigned short* __restrict__ xgb,  // [2][2048][1024] bf16 interleaved
    const unsigned char* __restrict__ w8fw,  // [1024][256] fp8 (x64)
    const unsigned char* __restrict__ w8bw,
    unsigned short* __restrict__ hcatb) {    // [64][32][512] bf16
  const int dir = blockIdx.x >> 1;
  const int nbase = (blockIdx.x & 1) * 16;
  const int tid = threadIdx.x;
  const int w = tid >> 6;
  const int l = tid & 63;
  const int ln15 = l & 15;
  const int kg = l >> 4;
  const int u_wave = w * 32;

  __shared__ unsigned char h8[2][16][256];    // fp8 h (x16), XOR-swizzled
  __shared__ unsigned short hx[2][256][18];   // bf16 h staging for hcat

  const unsigned char* W8 = dir ? w8bw : w8fw;

  // ---- fp8 weight fragments into registers (once; 128 VGPR) ----
  unsigned long long afrag[8][8];
  {
    int gate = ln15 & 3, du = ln15 >> 2;
#pragma unroll
    for (int mt = 0; mt < 8; ++mt) {
      const unsigned char* wr = W8 + (size_t)((gate << 8) + u_wave + mt * 4 + du) * 256;
#pragma unroll
      for (int kc = 0; kc < 8; ++kc)
        afrag[mt][kc] = *(const unsigned long long*)(wr + kc * 32 + kg * 8);
    }
  }

  const unsigned short* xgd = xgb + (size_t)dir * (2048u * 1024u);
  float cst[8] = {0.f, 0.f, 0.f, 0.f, 0.f, 0.f, 0.f, 0.f};
  f32x4 acc[8];

  // preload xg for step 0 (scaled by 1024 to match fp8 product scale)
  {
    int t0 = dir ? 63 : 0;
    const unsigned short* xb = xgd + (size_t)(t0 * 32 + nbase + ln15) * 1024;
#pragma unroll
    for (int mt = 0; mt < 8; ++mt) {
      ushort4v xv = *(const ushort4v*)(xb + (u_wave + mt * 4 + kg) * 4);
#pragma unroll
      for (int j = 0; j < 4; ++j) acc[mt][j] = b2f(xv[j]) * 1024.0f;
    }
  }

  const int swzw = (ln15 & 7) << 4;
  const float INV = 1.0f / 1024.0f;

  for (int s = 0; s < TSTEPS; ++s) {
    const int t = dir ? (63 - s) : s;
    const int p = s & 1;

    // ---- MFMA: acc += (64*W)(16*h) ----
    if (s > 0) {
      const unsigned char* hrow = &h8[p][ln15][0];
#pragma unroll
      for (int kc = 0; kc < 8; ++kc) {
        unsigned long long hb =
            *(const unsigned long long*)(hrow + ((kc * 32 + kg * 8) ^ swzw));
#pragma unroll
        for (int mt = 0; mt < 8; ++mt)
          acc[mt] = __builtin_amdgcn_mfma_f32_16x16x32_fp8_fp8(
              (long)afrag[mt][kc], (long)hb, acc[mt], 0, 0, 0);
      }
    }

    // ---- LSTM cell (lane-local; c in registers) ----
    {
      unsigned char* hw = &h8[p ^ 1][ln15][0];
#pragma unroll
      for (int mt = 0; mt < 8; ++mt) {
        float gi = sigm(acc[mt][0] * INV);
        float gf = sigm(acc[mt][1] * INV);
        float gg = tanh_fast(acc[mt][2] * INV);
        float go = sigm(acc[mt][3] * INV);
        float c = gf * cst[mt] + gi * gg;
        cst[mt] = c;
        float h = go * tanh_fast(c);
        int unit = u_wave + mt * 4 + kg;
        hw[unit ^ swzw] = fp8c(h * 16.0f);
        hx[p ^ 1][unit][ln15] = bf16c(h);
      }
    }

    // ---- prefetch next-step xg into acc ----
    if (s < TSTEPS - 1) {
      int tn2 = dir ? (t - 1) : (t + 1);
      const unsigned short* xb = xgd + (size_t)(tn2 * 32 + nbase + ln15) * 1024;
#pragma unroll
      for (int mt = 0; mt < 8; ++mt) {
        ushort4v xv = *(const ushort4v*)(xb + (u_wave + mt * 4 + kg) * 4);
#pragma unroll
        for (int j = 0; j < 4; ++j) acc[mt][j] = b2f(xv[j]) * 1024.0f;
      }
    }

    __syncthreads();

    // ---- coalesced hcat write (16 B/thread) ----
    {
      int n_loc = tid >> 5;            // 0..15
      int u0 = (tid & 31) * 8;         // 0..248
      short8 v;
#pragma unroll
      for (int q = 0; q < 8; ++q) v[q] = (short)hx[p ^ 1][u0 + q][n_loc];
      *(short8*)(hcatb + ((size_t)t * NSEQ + nbase + n_loc) * 512 + dir * 256 + u0) = v;
    }
  }
}

// ---------------- fused log-softmax + CTC loss ----------------
#define CTC_S 17
__global__ __launch_bounds__(576) void ctc_kernel(
    const float* __restrict__ preds,   // [64][32][12]
    const int* __restrict__ text,      // [256]
    const int* __restrict__ text_len,  // [32]
    float* __restrict__ out) {
  __shared__ float alpha[NSEQ][CTC_S];
  __shared__ float nalpha[NSEQ][CTC_S];
  __shared__ float lse[NSEQ];
  __shared__ int ext[NSEQ][CTC_S];
  __shared__ unsigned char allow[NSEQ][CTC_S];
  __shared__ unsigned char validm[NSEQ][CTC_S];
  __shared__ int tlsh[NSEQ];
  __shared__ float logp_sh[NSEQ];

  int tid = threadIdx.x;
  int b = tid & 31, sIdx = tid >> 5;
  bool active = sIdx < CTC_S;

  if (tid < NSEQ) tlsh[tid] = text_len[tid];
  __syncthreads();

  if (active) {
    int tl = tlsh[b];
    int off = 0;
    for (int i = 0; i < b; ++i) off += tlsh[i];
    int e = 0;
    if (sIdx & 1) {
      int lbl = (sIdx - 1) >> 1;
      int idx = off + lbl;
      if (idx > 255) idx = 255;
      e = (lbl < tl) ? text[idx] : 0;
    }
    ext[b][sIdx] = e;
    validm[b][sIdx] = (sIdx < 2 * tl + 1) ? 1 : 0;
  }
  __syncthreads();
  if (active) {
    int e = ext[b][sIdx];
    bool same2 = (sIdx >= 2) && (e == ext[b][sIdx - 2]);
    allow[b][sIdx] = ((sIdx >= 2) && (e != 0) && !same2) ? 1 : 0;
  }
  if (tid < NSEQ) {
    const float* p = preds + (size_t)b * 12;
    float mx = p[0];
    for (int k = 1; k < 12; ++k) mx = fmaxf(mx, p[k]);
    float ssum = 0.f;
    for (int k = 0; k < 12; ++k) ssum += expf(p[k] - mx);
    lse[b] = mx + logf(ssum);
  }
  __syncthreads();
  if (active) {
    float a = -1e30f;
    if (sIdx == 0) a = preds[(size_t)b * 12 + 0] - lse[b];
    else if (sIdx == 1 && tlsh[b] > 0) a = preds[(size_t)b * 12 + ext[b][1]] - lse[b];
    alpha[b][sIdx] = a;
  }
  __syncthreads();

  for (int t = 1; t < TSTEPS; ++t) {
    if (tid < NSEQ) {
      const float* p = preds + ((size_t)t * NSEQ + b) * 12;
      float mx = p[0];
      for (int k = 1; k < 12; ++k) mx = fmaxf(mx, p[k]);
      float ssum = 0.f;
      for (int k = 0; k < 12; ++k) ssum += expf(p[k] - mx);
      lse[b] = mx + logf(ssum);
    }
    __syncthreads();
    if (active) {
      float a = alpha[b][sIdx];
      float a1 = (sIdx >= 1) ? alpha[b][sIdx - 1] : -1e30f;
      float a2 = (sIdx >= 2 && allow[b][sIdx]) ? alpha[b][sIdx - 2] : -1e30f;
      float m = fmaxf(a, fmaxf(a1, a2));
      float ssum = expf(a - m) + expf(a1 - m) + expf(a2 - m);
      float emit = preds[((size_t)t * NSEQ + b) * 12 + ext[b][sIdx]] - lse[b];
      float nv = m + logf(ssum) + emit;
      nalpha[b][sIdx] = validm[b][sIdx] ? nv : -1e30f;
    }
    __syncthreads();
    if (active) alpha[b][sIdx] = nalpha[b][sIdx];
    __syncthreads();
  }

  if (tid < NSEQ) {
    int tl = tlsh[b];
    float a1 = alpha[b][2 * tl];
    float a2 = (tl > 0) ? alpha[b][2 * tl - 1] : -1e30f;
    float m = fmaxf(a1, a2);
    logp_sh[b] = m + logf(expf(a1 - m) + expf(a2 - m));
  }
  __syncthreads();
  if (tid == 0) {
    float ssum = 0.f;
    for (int i = 0; i < NSEQ; ++i) ssum += logp_sh[i];
    out[0] = -ssum / (float)NSEQ;
  }
}

// ---------------- launch ----------------
extern "C" void kernel_launch(void* const* d_in, const int* in_sizes, int n_in,
                              void* d_out, int out_size, void* d_ws, size_t ws_size,
                              hipStream_t stream) {
  (void)in_sizes; (void)n_in; (void)out_size; (void)ws_size;
  const float* base_feat = (const float*)d_in[0];
  const int* text = (const int*)d_in[1];
  const int* text_len = (const int*)d_in[2];
  const float* rois = (const float*)d_in[3];
  const float* l1_fw_W_ih = (const float*)d_in[4];
  const float* l1_fw_W_hh = (const float*)d_in[5];
  const float* l1_fw_b_ih = (const float*)d_in[6];
  const float* l1_fw_b_hh = (const float*)d_in[7];
  const float* l1_bw_W_ih = (const float*)d_in[8];
  const float* l1_bw_W_hh = (const float*)d_in[9];
  const float* l1_bw_b_ih = (const float*)d_in[10];
  const float* l1_bw_b_hh = (const float*)d_in[11];
  const float* l2_fw_W_ih = (const float*)d_in[12];
  const float* l2_fw_W_hh = (const float*)d_in[13];
  const float* l2_fw_b_ih = (const float*)d_in[14];
  const float* l2_fw_b_hh = (const float*)d_in[15];
  const float* l2_bw_W_ih = (const float*)d_in[16];
  const float* l2_bw_W_hh = (const float*)d_in[17];
  const float* l2_bw_b_ih = (const float*)d_in[18];
  const float* l2_bw_b_hh = (const float*)d_in[19];
  const float* W_emb1 = (const float*)d_in[20];
  const float* b_emb1 = (const float*)d_in[21];
  const float* W_emb2 = (const float*)d_in[22];
  const float* b_emb2 = (const float*)d_in[23];

  float* ws = (float*)d_ws;
  unsigned short* xgb  = (unsigned short*)(ws + OFF_XGB);
  unsigned short* rnnb = (unsigned short*)(ws + OFF_RNNB);
  unsigned short* w1fb = (unsigned short*)(ws + OFF_W1FB);
  unsigned short* w1bb = (unsigned short*)(ws + OFF_W1BB);
  unsigned short* w2fb = (unsigned short*)(ws + OFF_W2FB);
  unsigned short* w2bb = (unsigned short*)(ws + OFF_W2BB);
  unsigned short* we1b = (unsigned short*)(ws + OFF_WE1B);
  unsigned short* we2b = (unsigned short*)(ws + OFF_WE2B);
  unsigned char* w8l1f = (unsigned char*)(ws + OFF_W8L1F);
  unsigned char* w8l1b = (unsigned char*)(ws + OFF_W8L1B);
  unsigned char* w8l2f = (unsigned char*)(ws + OFF_W8L2F);
  unsigned char* w8l2b = (unsigned char*)(ws + OFF_W8L2B);
  unsigned short* hcb1 = (unsigned short*)(ws + OFF_HCB1);
  unsigned short* hcb2 = (unsigned short*)(ws + OFF_HCB2);
  unsigned short* h1b  = (unsigned short*)(ws + OFF_H1B);
  float* preds = ws + OFF_PREDS;

  // 0) weight conversions
  cvt_bf16<<<1024, 256, 0, stream>>>(l1_fw_W_ih, w1fb, 262144);
  cvt_bf16<<<1024, 256, 0, stream>>>(l1_bw_W_ih, w1bb, 262144);
  cvt_bf16<<<256, 256, 0, stream>>>(l2_fw_W_ih, w2fb, 65536);
  cvt_bf16<<<256, 256, 0, stream>>>(l2_bw_W_ih, w2bb, 65536);
  cvt_bf16<<<128, 256, 0, stream>>>(W_emb1, we1b, 32768);
  cvt_bf16<<<6, 256, 0, stream>>>(W_emb2, we2b, 1536);
  cvt_fp8<<<256, 256, 0, stream>>>(l1_fw_W_hh, w8l1f, 65536);
  cvt_fp8<<<256, 256, 0, stream>>>(l1_bw_W_hh, w8l1b, 65536);
  cvt_fp8<<<256, 256, 0, stream>>>(l2_fw_W_hh, w8l2f, 65536);
  cvt_fp8<<<256, 256, 0, stream>>>(l2_bw_W_hh, w8l2b, 65536);

  // 1) ROI max pool -> rnn bf16 [2048][1024]
  roi_pool_kernel<<<dim3(32, 256), 256, 0, stream>>>(base_feat, rois, rnnb);

  // 2) xg layer1 (mode 3: bf16 interleaved [tn][unit*4+gate])
  gemm_bf16<<<dim3(16, 8), 256, 0, stream>>>(w1fb, rnnb, nullptr, xgb,
      1024, 2048, 1024, l1_fw_b_ih, l1_fw_b_hh, nullptr, 3);
  gemm_bf16<<<dim3(16, 8), 256, 0, stream>>>(w1bb, rnnb, nullptr, xgb + 2097152u,
      1024, 2048, 1024, l1_bw_b_ih, l1_bw_b_hh, nullptr, 3);

  // 3) layer-1 recurrence (4 independent blocks, fp8 weights in registers)
  lstm_layer5<<<4, 512, 0, stream>>>(xgb, w8l1f, w8l1b, hcb1);

  // 4) h1 = hcat1 @ W_emb1^T + b_emb1 -> bf16
  gemm_bf16<<<dim3(2, 16), 256, 0, stream>>>(hcb1, we1b, nullptr, h1b,
      2048, 256, 512, nullptr, nullptr, b_emb1, 1);

  // 5) xg layer2 (mode 3)
  gemm_bf16<<<dim3(16, 8), 256, 0, stream>>>(w2fb, h1b, nullptr, xgb,
      1024, 2048, 256, l2_fw_b_ih, l2_fw_b_hh, nullptr, 3);
  gemm_bf16<<<dim3(16, 8), 256, 0, stream>>>(w2bb, h1b, nullptr, xgb + 2097152u,
      1024, 2048, 256, l2_bw_b_ih, l2_bw_b_hh, nullptr, 3);

  // 6) layer-2 recurrence
  lstm_layer5<<<4, 512, 0, stream>>>(xgb, w8l2f, w8l2b, hcb2);

  // 7) preds = hcat2 @ W_emb2^T + b_emb2 (f32, N=12 guarded)
  gemm_bf16<<<dim3(1, 16), 256, 0, stream>>>(hcb2, we2b, preds, nullptr,
      2048, 12, 512, nullptr, nullptr, b_emb2, 0);

  // 8) log-softmax + CTC
  ctc_kernel<<<1, 576, 0, stream>>>(preds, text, text_len, (float*)d_out);
}

// Round 7
// 682.127 us; speedup vs baseline: 2.9458x; 1.3440x over previous
//
#include <hip/hip_runtime.h>
#include <math.h>

// ---------------- problem constants ----------------
#define TSTEPS 64
#define NSEQ   32
#define FH     40
#define FW     160

// ---------------- workspace layout (float units) ----------------
#define OFF_XGB    0u            // [2][2048][1024] bf16 interleaved (tn, unit*4+gate), x1024
#define OFF_RNNB   2097152u      // [2048][1024] bf16
#define OFF_W1FB   3145728u      // l1 fw W_ih bf16 1024x1024
#define OFF_W1BB   3670016u
#define OFF_W2FB   4194304u      // l2 fw W_ih bf16 1024x256
#define OFF_W2BB   4325376u
#define OFF_WE1B   4456448u      // W_emb1 bf16 256x512
#define OFF_WE2B   4521984u      // W_emb2 bf16 12x512
#define OFF_W8L1F  4526080u      // l1 fw W_hh fp8 (x64), k-permuted, 1024x256
#define OFF_W8L1B  4591616u
#define OFF_W8L2F  4657152u
#define OFF_W8L2B  4722688u
#define OFF_HCB1   4788224u      // hcat1 bf16 [2048][512]
#define OFF_HCB2   5312512u
#define OFF_H1B    5836800u      // h1 bf16 [2048][256]
#define OFF_PREDS  6098944u      // [2048][12] f32

typedef __attribute__((ext_vector_type(8))) short short8;
typedef __attribute__((ext_vector_type(4))) float f32x4;
typedef __attribute__((ext_vector_type(4))) unsigned short ushort4v;

static __device__ inline unsigned short bf16c(float x) {
  union { float f; unsigned u; } v; v.f = x;
  unsigned r = v.u + 0x7fff + ((v.u >> 16) & 1);   // RNE
  return (unsigned short)(r >> 16);
}
static __device__ inline float b2f(unsigned short u) {
  union { unsigned u; float f; } v; v.u = ((unsigned)u) << 16;
  return v.f;
}
// f32 -> fp8 e4m3fn (OCP): RNE, saturate, flush subnormals
static __device__ inline unsigned char fp8c(float x) {
  union { float f; unsigned u; } v; v.f = x;
  unsigned s = (v.u >> 24) & 0x80;
  float ax = fabsf(x);
  if (ax < 0.015625f) return (unsigned char)s;
  if (ax >= 448.0f) return (unsigned char)(s | 0x7e);
  unsigned e = (v.u >> 23) & 0xff;
  unsigned m = v.u & 0x7fffff;
  unsigned r = m + 0x7ffff + ((m >> 20) & 1);
  if (r >> 23) { e += 1; r = 0; }
  unsigned m3 = (r >> 20) & 7;
  int ee = (int)e - 127 + 7;
  if (ee > 15) return (unsigned char)(s | 0x7e);
  return (unsigned char)(s | (ee << 3) | m3);
}

// pack 4 floats (pre-scaled) -> 4 fp8 bytes in a dword
static __device__ inline unsigned pk4_fp8(float a, float b, float c, float d) {
#if __has_builtin(__builtin_amdgcn_cvt_pk_fp8_f32)
  int r = __builtin_amdgcn_cvt_pk_fp8_f32(a, b, 0, false);
  r = __builtin_amdgcn_cvt_pk_fp8_f32(c, d, r, true);
  return (unsigned)r;
#else
  return (unsigned)fp8c(a) | ((unsigned)fp8c(b) << 8)
       | ((unsigned)fp8c(c) << 16) | ((unsigned)fp8c(d) << 24);
#endif
}

// ---------------- f32 -> bf16 converter ----------------
__global__ __launch_bounds__(256) void cvt_bf16(
    const float* __restrict__ in, unsigned short* __restrict__ out, int n4) {
  int i = blockIdx.x * 256 + threadIdx.x;
  if (i < n4) {
    float4 v = ((const float4*)in)[i];
    ushort4v o;
    o[0] = bf16c(v.x); o[1] = bf16c(v.y); o[2] = bf16c(v.z); o[3] = bf16c(v.w);
    ((ushort4v*)out)[i] = o;
  }
}

// ---------------- W_hh f32 -> fp8 (x64), k-permuted: out[row][pi(u)] = W[row][u],
// pi(u) = (u&3)*64 + (u>>2)  (inverse: u = (k'>>6) + (k'&63)*4) ----------------
__global__ __launch_bounds__(256) void cvt_fp8w(
    const float* __restrict__ in, unsigned char* __restrict__ out) {
  int idx = blockIdx.x * 256 + threadIdx.x;   // dword index, 65536 total
  int row = idx >> 6;
  int k4 = (idx & 63) * 4;
  const float* r = in + (size_t)row * 256;
  unsigned o = 0;
#pragma unroll
  for (int j = 0; j < 4; ++j) {
    int kp = k4 + j;
    int u = (kp >> 6) + (kp & 63) * 4;
    o |= ((unsigned)fp8c(r[u] * 64.0f)) << (8 * j);
  }
  ((unsigned*)out)[idx] = o;
}

// ---------------- ROI max pool -> rnn bf16 [t*32+n][c*2+ph] ----------------
__global__ __launch_bounds__(256) void roi_pool_kernel(
    const float* __restrict__ feat, const float* __restrict__ rois,
    unsigned short* __restrict__ rnn) {
  int n  = blockIdx.x;
  int cg = blockIdx.y;
  int tid = threadIdx.x;
  int pw = tid & 63, ph = (tid >> 6) & 1, cl = tid >> 7;
  int c = cg * 2 + cl;

  const float* r = rois + n * 5;
  int bi = (int)r[0];
  int x1 = (int)rintf(r[1] * (float)FW);
  int y1 = (int)rintf(r[2] * (float)FH);
  int x2 = (int)rintf(r[3] * (float)FW);
  int y2 = (int)rintf(r[4] * (float)FH);
  float rw = fmaxf((float)(x2 - x1 + 1), 1.0f);
  float rh = fmaxf((float)(y2 - y1 + 1), 1.0f);
  float bin_h = rh * 0.5f;
  float bin_w = rw * (1.0f / 64.0f);

  int hs = min(max((int)floorf((float)ph * bin_h) + y1, 0), FH);
  int he = min(max((int)ceilf((float)(ph + 1) * bin_h) + y1, 0), FH);
  int wst = min(max((int)floorf((float)pw * bin_w) + x1, 0), FW);
  int wen = min(max((int)ceilf((float)(pw + 1) * bin_w) + x1, 0), FW);

  float m = -1e30f;
  bool nonempty = (hs < he) && (wst < wen);
  const float* f = feat + ((size_t)bi * 512 + c) * (FH * FW);
  for (int h = hs; h < he; ++h) {
    const float* fr = f + h * FW;
    for (int w = wst; w < wen; ++w) m = fmaxf(m, fr[w]);
  }
  float out = nonempty ? m : 0.0f;
  rnn[((size_t)pw * NSEQ + n) * 1024 + c * 2 + ph] = bf16c(out);
}

// ---------------- bf16 MFMA GEMM ----------------
// mode 0: Cf[m*N+n] f32; mode 1: Cb[m*N+n] bf16;
// mode 3: Cb[n*1024 + (m&255)*4 + (m>>8)] bf16 of 1024*v (xg interleave, M=1024)
#define GPITCH 40
__global__ __launch_bounds__(256) void gemm_bf16(
    const unsigned short* __restrict__ A, const unsigned short* __restrict__ B,
    float* __restrict__ Cf, unsigned short* __restrict__ Cb,
    int M, int N, int K,
    const float* __restrict__ bm1, const float* __restrict__ bm2,
    const float* __restrict__ bn, int mode) {
  __shared__ unsigned short Al[128 * GPITCH];
  __shared__ unsigned short Bl[128 * GPITCH];
  int m0 = blockIdx.y * 128, n0 = blockIdx.x * 128;
  int tid = threadIdx.x;
  int wid = tid >> 6, l = tid & 63, ln15 = l & 15, kg = l >> 4;
  int wm = wid >> 1, wn = wid & 1;

  f32x4 acc[4][4];
#pragma unroll
  for (int i = 0; i < 4; ++i)
#pragma unroll
    for (int j = 0; j < 4; ++j)
#pragma unroll
      for (int q = 0; q < 4; ++q) acc[i][j][q] = 0.0f;

  for (int k0 = 0; k0 < K; k0 += 32) {
#pragma unroll
    for (int it = 0; it < 2; ++it) {
      int chunk = tid + it * 256;
      int row = chunk >> 2, part = chunk & 3;
      short8 va = *(const short8*)(A + (size_t)(m0 + row) * K + k0 + part * 8);
      *(short8*)(Al + row * GPITCH + part * 8) = va;
      short8 vb;
      if (n0 + row < N) {
        vb = *(const short8*)(B + (size_t)(n0 + row) * K + k0 + part * 8);
      } else {
#pragma unroll
        for (int q = 0; q < 8; ++q) vb[q] = 0;
      }
      *(short8*)(Bl + row * GPITCH + part * 8) = vb;
    }
    __syncthreads();

    short8 a[4], b[4];
#pragma unroll
    for (int mt = 0; mt < 4; ++mt)
      a[mt] = *(const short8*)(Al + (wm * 64 + mt * 16 + ln15) * GPITCH + kg * 8);
#pragma unroll
    for (int nt = 0; nt < 4; ++nt)
      b[nt] = *(const short8*)(Bl + (wn * 64 + nt * 16 + ln15) * GPITCH + kg * 8);
#pragma unroll
    for (int mt = 0; mt < 4; ++mt)
#pragma unroll
      for (int nt = 0; nt < 4; ++nt)
        acc[mt][nt] = __builtin_amdgcn_mfma_f32_16x16x32_bf16(a[mt], b[nt], acc[mt][nt], 0, 0, 0);
    __syncthreads();
  }

#pragma unroll
  for (int mt = 0; mt < 4; ++mt) {
#pragma unroll
    for (int j = 0; j < 4; ++j) {
      int m = m0 + wm * 64 + mt * 16 + kg * 4 + j;
      float bmv = 0.0f;
      if (bm1) bmv += bm1[m];
      if (bm2) bmv += bm2[m];
#pragma unroll
      for (int nt = 0; nt < 4; ++nt) {
        int n = n0 + wn * 64 + nt * 16 + ln15;
        float v = acc[mt][nt][j] + bmv;
        if (bn && n < N) v += bn[n];
        if (mode == 3) {
          Cb[(size_t)n * 1024 + (m & 255) * 4 + (m >> 8)] = bf16c(v * 1024.0f);
        } else if (n < N) {
          if (mode == 1) Cb[(size_t)m * N + n] = bf16c(v);
          else Cf[(size_t)m * N + n] = v;
        }
      }
    }
  }
}

// ---------------- persistent BiLSTM layer v6: fp8 reg weights, early prefetch ----
// Grid 4 blocks: dir = blk>>1, batch-half = blk&1 (16 n). 512 thr = 8 waves.
// afrag[8][8] u64 = 128 VGPR; xg prefetched into xnext at TOP of iteration so the
// barrier's vmcnt(0) drain is free. h stored fp8 (x16) as ONE ds_write_b64 per
// lane into the k-permuted slot pi(u)=(u&3)*64+(u>>2) matching the W permute.
__global__ __launch_bounds__(512, 2) void lstm_layer6(
    const unsigned short* __restrict__ xgb,  // [2][2048][1024] bf16, value = 1024*xg
    const unsigned char* __restrict__ w8fw,  // [1024][256] fp8 (x64), k-permuted
    const unsigned char* __restrict__ w8bw,
    unsigned short* __restrict__ hcatb) {    // [64][32][512] bf16
  const int dir = blockIdx.x >> 1;
  const int nbase = (blockIdx.x & 1) * 16;
  const int tid = threadIdx.x;
  const int w = tid >> 6;
  const int l = tid & 63;
  const int ln15 = l & 15;
  const int kg = l >> 4;
  const int u_wave = w * 32;

  __shared__ unsigned char h8[2][16][256];    // fp8 h (x16), k-permuted + swizzled
  __shared__ unsigned short hx[2][256][18];   // bf16 h staging for hcat

  const unsigned char* W8 = dir ? w8bw : w8fw;

  // ---- fp8 weight fragments into registers (once; 128 VGPR) ----
  unsigned long long afrag[8][8];
  {
    int gate = ln15 & 3, du = ln15 >> 2;
#pragma unroll
    for (int mt = 0; mt < 8; ++mt) {
      const unsigned char* wr = W8 + (size_t)((gate << 8) + u_wave + mt * 4 + du) * 256;
#pragma unroll
      for (int kc = 0; kc < 8; ++kc)
        afrag[mt][kc] = *(const unsigned long long*)(wr + kc * 32 + kg * 8);
    }
  }

  const unsigned short* xgd = xgb + (size_t)dir * (2048u * 1024u);
  float cst[8] = {0.f, 0.f, 0.f, 0.f, 0.f, 0.f, 0.f, 0.f};
  f32x4 acc[8];
  ushort4v xnext[8];

  // step-0 xg (already x1024)
  {
    int t0 = dir ? 63 : 0;
    const unsigned short* xb = xgd + (size_t)(t0 * 32 + nbase + ln15) * 1024;
#pragma unroll
    for (int mt = 0; mt < 8; ++mt)
      xnext[mt] = *(const ushort4v*)(xb + (u_wave + mt * 4 + kg) * 4);
#pragma unroll
    for (int mt = 0; mt < 8; ++mt)
#pragma unroll
      for (int j = 0; j < 4; ++j) acc[mt][j] = b2f(xnext[mt][j]);
  }

  const int swzw = (ln15 & 7) << 4;
  const int myslot = kg * 64 + w * 8;           // permuted byte slot of this lane's 8 h
  const float kNI = -1.0f / 1024.0f;            // folded -INV
  const float kP2 = 2.0f / 1024.0f;             // folded 2*INV

  for (int s = 0; s < TSTEPS; ++s) {
    const int t = dir ? (63 - s) : s;
    const int p = s & 1;

    // ---- A) issue next-step xg loads FIRST (latency hides under MFMA+cell) ----
    if (s < TSTEPS - 1) {
      int tn2 = dir ? (t - 1) : (t + 1);
      const unsigned short* xb = xgd + (size_t)(tn2 * 32 + nbase + ln15) * 1024;
#pragma unroll
      for (int mt = 0; mt < 8; ++mt)
        xnext[mt] = *(const ushort4v*)(xb + (u_wave + mt * 4 + kg) * 4);
    }

    // ---- B) MFMA: acc += (64*W)(16*h) ----
    if (s > 0) {
      const unsigned char* hrow = &h8[p][ln15][0];
#pragma unroll
      for (int kc = 0; kc < 8; ++kc) {
        unsigned long long hb =
            *(const unsigned long long*)(hrow + ((kc * 32 + kg * 8) ^ swzw));
#pragma unroll
        for (int mt = 0; mt < 8; ++mt)
          acc[mt] = __builtin_amdgcn_mfma_f32_16x16x32_fp8_fp8(
              (long)afrag[mt][kc], (long)hb, acc[mt], 0, 0, 0);
      }
    }

    // ---- C) LSTM cell: gates, c, h; packed fp8 store; acc re-init from xnext ----
    {
      float hv[8];
#pragma unroll
      for (int mt = 0; mt < 8; ++mt) {
        float gi = __builtin_amdgcn_rcpf(1.0f + __expf(acc[mt][0] * kNI));
        float gf = __builtin_amdgcn_rcpf(1.0f + __expf(acc[mt][1] * kNI));
        float gg = 1.0f - 2.0f * __builtin_amdgcn_rcpf(1.0f + __expf(acc[mt][2] * kP2));
        float go = __builtin_amdgcn_rcpf(1.0f + __expf(acc[mt][3] * kNI));
        float c = gf * cst[mt] + gi * gg;
        cst[mt] = c;
        float h = go * (1.0f - 2.0f * __builtin_amdgcn_rcpf(1.0f + __expf(2.0f * c)));
        hv[mt] = h;
        hx[p ^ 1][u_wave + mt * 4 + kg][ln15] = bf16c(h);
      }
      unsigned d0 = pk4_fp8(hv[0] * 16.f, hv[1] * 16.f, hv[2] * 16.f, hv[3] * 16.f);
      unsigned d1 = pk4_fp8(hv[4] * 16.f, hv[5] * 16.f, hv[6] * 16.f, hv[7] * 16.f);
      unsigned long long pk = (unsigned long long)d0 | ((unsigned long long)d1 << 32);
      *(unsigned long long*)(&h8[p ^ 1][ln15][0] + (myslot ^ swzw)) = pk;

      if (s < TSTEPS - 1) {
#pragma unroll
        for (int mt = 0; mt < 8; ++mt)
#pragma unroll
          for (int j = 0; j < 4; ++j) acc[mt][j] = b2f(xnext[mt][j]);
      }
    }

    __syncthreads();

    // ---- D) coalesced hcat write (16 B/thread) ----
    {
      int n_loc = tid >> 5;            // 0..15
      int u0 = (tid & 31) * 8;         // 0..248
      short8 v;
#pragma unroll
      for (int q = 0; q < 8; ++q) v[q] = (short)hx[p ^ 1][u0 + q][n_loc];
      *(short8*)(hcatb + ((size_t)t * NSEQ + nbase + n_loc) * 512 + dir * 256 + u0) = v;
    }
  }
}

// ---------------- fused log-softmax + CTC loss ----------------
#define CTC_S 17
__global__ __launch_bounds__(576) void ctc_kernel(
    const float* __restrict__ preds,   // [64][32][12]
    const int* __restrict__ text,      // [256]
    const int* __restrict__ text_len,  // [32]
    float* __restrict__ out) {
  __shared__ float alpha[NSEQ][CTC_S];
  __shared__ float nalpha[NSEQ][CTC_S];
  __shared__ float lse[NSEQ];
  __shared__ int ext[NSEQ][CTC_S];
  __shared__ unsigned char allow[NSEQ][CTC_S];
  __shared__ unsigned char validm[NSEQ][CTC_S];
  __shared__ int tlsh[NSEQ];
  __shared__ float logp_sh[NSEQ];

  int tid = threadIdx.x;
  int b = tid & 31, sIdx = tid >> 5;
  bool active = sIdx < CTC_S;

  if (tid < NSEQ) tlsh[tid] = text_len[tid];
  __syncthreads();

  if (active) {
    int tl = tlsh[b];
    int off = 0;
    for (int i = 0; i < b; ++i) off += tlsh[i];
    int e = 0;
    if (sIdx & 1) {
      int lbl = (sIdx - 1) >> 1;
      int idx = off + lbl;
      if (idx > 255) idx = 255;
      e = (lbl < tl) ? text[idx] : 0;
    }
    ext[b][sIdx] = e;
    validm[b][sIdx] = (sIdx < 2 * tl + 1) ? 1 : 0;
  }
  __syncthreads();
  if (active) {
    int e = ext[b][sIdx];
    bool same2 = (sIdx >= 2) && (e == ext[b][sIdx - 2]);
    allow[b][sIdx] = ((sIdx >= 2) && (e != 0) && !same2) ? 1 : 0;
  }
  if (tid < NSEQ) {
    const float* p = preds + (size_t)b * 12;
    float mx = p[0];
    for (int k = 1; k < 12; ++k) mx = fmaxf(mx, p[k]);
    float ssum = 0.f;
    for (int k = 0; k < 12; ++k) ssum += expf(p[k] - mx);
    lse[b] = mx + logf(ssum);
  }
  __syncthreads();
  if (active) {
    float a = -1e30f;
    if (sIdx == 0) a = preds[(size_t)b * 12 + 0] - lse[b];
    else if (sIdx == 1 && tlsh[b] > 0) a = preds[(size_t)b * 12 + ext[b][1]] - lse[b];
    alpha[b][sIdx] = a;
  }
  __syncthreads();

  for (int t = 1; t < TSTEPS; ++t) {
    if (tid < NSEQ) {
      const float* p = preds + ((size_t)t * NSEQ + b) * 12;
      float mx = p[0];
      for (int k = 1; k < 12; ++k) mx = fmaxf(mx, p[k]);
      float ssum = 0.f;
      for (int k = 0; k < 12; ++k) ssum += expf(p[k] - mx);
      lse[b] = mx + logf(ssum);
    }
    __syncthreads();
    if (active) {
      float a = alpha[b][sIdx];
      float a1 = (sIdx >= 1) ? alpha[b][sIdx - 1] : -1e30f;
      float a2 = (sIdx >= 2 && allow[b][sIdx]) ? alpha[b][sIdx - 2] : -1e30f;
      float m = fmaxf(a, fmaxf(a1, a2));
      float ssum = expf(a - m) + expf(a1 - m) + expf(a2 - m);
      float emit = preds[((size_t)t * NSEQ + b) * 12 + ext[b][sIdx]] - lse[b];
      float nv = m + logf(ssum) + emit;
      nalpha[b][sIdx] = validm[b][sIdx] ? nv : -1e30f;
    }
    __syncthreads();
    if (active) alpha[b][sIdx] = nalpha[b][sIdx];
    __syncthreads();
  }

  if (tid < NSEQ) {
    int tl = tlsh[b];
    float a1 = alpha[b][2 * tl];
    float a2 = (tl > 0) ? alpha[b][2 * tl - 1] : -1e30f;
    float m = fmaxf(a1, a2);
    logp_sh[b] = m + logf(expf(a1 - m) + expf(a2 - m));
  }
  __syncthreads();
  if (tid == 0) {
    float ssum = 0.f;
    for (int i = 0; i < NSEQ; ++i) ssum += logp_sh[i];
    out[0] = -ssum / (float)NSEQ;
  }
}

// ---------------- launch ----------------
extern "C" void kernel_launch(void* const* d_in, const int* in_sizes, int n_in,
                              void* d_out, int out_size, void* d_ws, size_t ws_size,
                              hipStream_t stream) {
  (void)in_sizes; (void)n_in; (void)out_size; (void)ws_size;
  const float* base_feat = (const float*)d_in[0];
  const int* text = (const int*)d_in[1];
  const int* text_len = (const int*)d_in[2];
  const float* rois = (const float*)d_in[3];
  const float* l1_fw_W_ih = (const float*)d_in[4];
  const float* l1_fw_W_hh = (const float*)d_in[5];
  const float* l1_fw_b_ih = (const float*)d_in[6];
  const float* l1_fw_b_hh = (const float*)d_in[7];
  const float* l1_bw_W_ih = (const float*)d_in[8];
  const float* l1_bw_W_hh = (const float*)d_in[9];
  const float* l1_bw_b_ih = (const float*)d_in[10];
  const float* l1_bw_b_hh = (const float*)d_in[11];
  const float* l2_fw_W_ih = (const float*)d_in[12];
  const float* l2_fw_W_hh = (const float*)d_in[13];
  const float* l2_fw_b_ih = (const float*)d_in[14];
  const float* l2_fw_b_hh = (const float*)d_in[15];
  const float* l2_bw_W_ih = (const float*)d_in[16];
  const float* l2_bw_W_hh = (const float*)d_in[17];
  const float* l2_bw_b_ih = (const float*)d_in[18];
  const float* l2_bw_b_hh = (const float*)d_in[19];
  const float* W_emb1 = (const float*)d_in[20];
  const float* b_emb1 = (const float*)d_in[21];
  const float* W_emb2 = (const float*)d_in[22];
  const float* b_emb2 = (const float*)d_in[23];

  float* ws = (float*)d_ws;
  unsigned short* xgb  = (unsigned short*)(ws + OFF_XGB);
  unsigned short* rnnb = (unsigned short*)(ws + OFF_RNNB);
  unsigned short* w1fb = (unsigned short*)(ws + OFF_W1FB);
  unsigned short* w1bb = (unsigned short*)(ws + OFF_W1BB);
  unsigned short* w2fb = (unsigned short*)(ws + OFF_W2FB);
  unsigned short* w2bb = (unsigned short*)(ws + OFF_W2BB);
  unsigned short* we1b = (unsigned short*)(ws + OFF_WE1B);
  unsigned short* we2b = (unsigned short*)(ws + OFF_WE2B);
  unsigned char* w8l1f = (unsigned char*)(ws + OFF_W8L1F);
  unsigned char* w8l1b = (unsigned char*)(ws + OFF_W8L1B);
  unsigned char* w8l2f = (unsigned char*)(ws + OFF_W8L2F);
  unsigned char* w8l2b = (unsigned char*)(ws + OFF_W8L2B);
  unsigned short* hcb1 = (unsigned short*)(ws + OFF_HCB1);
  unsigned short* hcb2 = (unsigned short*)(ws + OFF_HCB2);
  unsigned short* h1b  = (unsigned short*)(ws + OFF_H1B);
  float* preds = ws + OFF_PREDS;

  // 0) weight conversions
  cvt_bf16<<<1024, 256, 0, stream>>>(l1_fw_W_ih, w1fb, 262144);
  cvt_bf16<<<1024, 256, 0, stream>>>(l1_bw_W_ih, w1bb, 262144);
  cvt_bf16<<<256, 256, 0, stream>>>(l2_fw_W_ih, w2fb, 65536);
  cvt_bf16<<<256, 256, 0, stream>>>(l2_bw_W_ih, w2bb, 65536);
  cvt_bf16<<<128, 256, 0, stream>>>(W_emb1, we1b, 32768);
  cvt_bf16<<<6, 256, 0, stream>>>(W_emb2, we2b, 1536);
  cvt_fp8w<<<256, 256, 0, stream>>>(l1_fw_W_hh, w8l1f);
  cvt_fp8w<<<256, 256, 0, stream>>>(l1_bw_W_hh, w8l1b);
  cvt_fp8w<<<256, 256, 0, stream>>>(l2_fw_W_hh, w8l2f);
  cvt_fp8w<<<256, 256, 0, stream>>>(l2_bw_W_hh, w8l2b);

  // 1) ROI max pool -> rnn bf16 [2048][1024]
  roi_pool_kernel<<<dim3(32, 256), 256, 0, stream>>>(base_feat, rois, rnnb);

  // 2) xg layer1 (mode 3: bf16 interleaved, x1024)
  gemm_bf16<<<dim3(16, 8), 256, 0, stream>>>(w1fb, rnnb, nullptr, xgb,
      1024, 2048, 1024, l1_fw_b_ih, l1_fw_b_hh, nullptr, 3);
  gemm_bf16<<<dim3(16, 8), 256, 0, stream>>>(w1bb, rnnb, nullptr, xgb + 2097152u,
      1024, 2048, 1024, l1_bw_b_ih, l1_bw_b_hh, nullptr, 3);

  // 3) layer-1 recurrence
  lstm_layer6<<<4, 512, 0, stream>>>(xgb, w8l1f, w8l1b, hcb1);

  // 4) h1 = hcat1 @ W_emb1^T + b_emb1 -> bf16
  gemm_bf16<<<dim3(2, 16), 256, 0, stream>>>(hcb1, we1b, nullptr, h1b,
      2048, 256, 512, nullptr, nullptr, b_emb1, 1);

  // 5) xg layer2 (mode 3)
  gemm_bf16<<<dim3(16, 8), 256, 0, stream>>>(w2fb, h1b, nullptr, xgb,
      1024, 2048, 256, l2_fw_b_ih, l2_fw_b_hh, nullptr, 3);
  gemm_bf16<<<dim3(16, 8), 256, 0, stream>>>(w2bb, h1b, nullptr, xgb + 2097152u,
      1024, 2048, 256, l2_bw_b_ih, l2_bw_b_hh, nullptr, 3);

  // 6) layer-2 recurrence
  lstm_layer6<<<4, 512, 0, stream>>>(xgb, w8l2f, w8l2b, hcb2);

  // 7) preds = hcat2 @ W_emb2^T + b_emb2 (f32, N=12 guarded)
  gemm_bf16<<<dim3(1, 16), 256, 0, stream>>>(hcb2, we2b, preds, nullptr,
      2048, 12, 512, nullptr, nullptr, b_emb2, 0);

  // 8) log-softmax + CTC
  ctc_kernel<<<1, 576, 0, stream>>>(preds, text, text_len, (float*)d_out);
}

// Round 8
// 546.898 us; speedup vs baseline: 3.6742x; 1.2473x over previous
//
#include <hip/hip_runtime.h>
#include <math.h>

// ---------------- problem constants ----------------
#define TSTEPS 64
#define NSEQ   32
#define FH     40
#define FW     160

// ---------------- workspace layout (float units) ----------------
#define OFF_XGB    0u            // [2][64 t][256 unit][32 n][4 gate] bf16, x1024
#define OFF_RNNB   2097152u      // [2048 tn][1024] bf16
#define OFF_W12B   3145728u      // W_ih l1 bf16, row-permuted unit*4+gate, [2048][1024]
#define OFF_W22B   4194304u      // W_ih l2 bf16 permuted [2048][256]
#define OFF_WE1B   4456448u      // W_emb1 bf16 [256][512]
#define OFF_WE2B   4521984u      // W_emb2 bf16 [12][512]
#define OFF_PB1    4525056u      // combined permuted bias l1 [2048] f32
#define OFF_PB2    4527104u      // combined permuted bias l2 [2048] f32
#define OFF_W8L1F  4529152u      // W_hh fp8 (x64) k-permuted [1024][256]
#define OFF_W8L1B  4594688u
#define OFF_W8L2F  4660224u
#define OFF_W8L2B  4725760u
#define OFF_HCB1   4791296u      // hcat1 bf16 [2048][512]
#define OFF_HCB2   5315584u
#define OFF_H1B    5839872u      // h1 bf16 [2048][256]
#define OFF_PREDS  6102016u      // [2048][12] f32

typedef __attribute__((ext_vector_type(8))) short short8;
typedef __attribute__((ext_vector_type(4))) float f32x4;
typedef __attribute__((ext_vector_type(4))) unsigned short ushort4v;

static __device__ inline unsigned short bf16c(float x) {
  union { float f; unsigned u; } v; v.f = x;
  unsigned r = v.u + 0x7fff + ((v.u >> 16) & 1);   // RNE
  return (unsigned short)(r >> 16);
}
static __device__ inline float b2f(unsigned short u) {
  union { unsigned u; float f; } v; v.u = ((unsigned)u) << 16;
  return v.f;
}
// f32 -> fp8 e4m3fn (OCP): RNE, saturate, flush subnormals
static __device__ inline unsigned char fp8c(float x) {
  union { float f; unsigned u; } v; v.f = x;
  unsigned s = (v.u >> 24) & 0x80;
  float ax = fabsf(x);
  if (ax < 0.015625f) return (unsigned char)s;
  if (ax >= 448.0f) return (unsigned char)(s | 0x7e);
  unsigned e = (v.u >> 23) & 0xff;
  unsigned m = v.u & 0x7fffff;
  unsigned r = m + 0x7ffff + ((m >> 20) & 1);
  if (r >> 23) { e += 1; r = 0; }
  unsigned m3 = (r >> 20) & 7;
  int ee = (int)e - 127 + 7;
  if (ee > 15) return (unsigned char)(s | 0x7e);
  return (unsigned char)(s | (ee << 3) | m3);
}
static __device__ inline unsigned pk4_fp8(float a, float b, float c, float d) {
#if __has_builtin(__builtin_amdgcn_cvt_pk_fp8_f32)
  int r = __builtin_amdgcn_cvt_pk_fp8_f32(a, b, 0, false);
  r = __builtin_amdgcn_cvt_pk_fp8_f32(c, d, r, true);
  return (unsigned)r;
#else
  return (unsigned)fp8c(a) | ((unsigned)fp8c(b) << 8)
       | ((unsigned)fp8c(c) << 16) | ((unsigned)fp8c(d) << 24);
#endif
}

// ---------------- single prep kernel: all weight/bias conversions ----------------
// blocks: [0,2048) l1 W_ih bf16 perm | [2048,2560) l2 W_ih | [2560,2688) we1 |
// [2688,2694) we2 | [2694,3718) fp8 W_hh x4 | [3718,3726) pb1 | [3726,3734) pb2
__global__ __launch_bounds__(256) void prep_kernel(
    const float* __restrict__ w1f, const float* __restrict__ w1b,
    const float* __restrict__ w2f, const float* __restrict__ w2b,
    const float* __restrict__ we1, const float* __restrict__ we2,
    const float* __restrict__ wh1f, const float* __restrict__ wh1b,
    const float* __restrict__ wh2f, const float* __restrict__ wh2b,
    const float* __restrict__ b1fi, const float* __restrict__ b1fh,
    const float* __restrict__ b1bi, const float* __restrict__ b1bh,
    const float* __restrict__ b2fi, const float* __restrict__ b2fh,
    const float* __restrict__ b2bi, const float* __restrict__ b2bh,
    unsigned short* __restrict__ w12b, unsigned short* __restrict__ w22b,
    unsigned short* __restrict__ we1o, unsigned short* __restrict__ we2o,
    unsigned char* __restrict__ o8l1f, unsigned char* __restrict__ o8l1b,
    unsigned char* __restrict__ o8l2f, unsigned char* __restrict__ o8l2b,
    float* __restrict__ pb1, float* __restrict__ pb2) {
  int b = blockIdx.x, tid = threadIdx.x;
  if (b < 2048) {
    const float* src = (b < 1024) ? w1f : w1b;
    unsigned short* dst = w12b + (size_t)((b < 1024) ? 0 : 1048576);
    int i = (b & 1023) * 256 + tid;            // f4 idx in [1024 rows][256 f4]
    int row = i >> 8, c4 = i & 255;
    int orow = (row & 255) * 4 + (row >> 8);   // gate*256+unit -> unit*4+gate
    float4 v = ((const float4*)src)[i];
    ushort4v o; o[0]=bf16c(v.x); o[1]=bf16c(v.y); o[2]=bf16c(v.z); o[3]=bf16c(v.w);
    *(ushort4v*)(dst + (size_t)orow * 1024 + c4 * 4) = o;
  } else if (b < 2560) {
    int bb = b - 2048;
    const float* src = (bb < 256) ? w2f : w2b;
    unsigned short* dst = w22b + (size_t)((bb < 256) ? 0 : 262144);
    int i = (bb & 255) * 256 + tid;            // f4 idx in [1024 rows][64 f4]
    int row = i >> 6, c4 = i & 63;
    int orow = (row & 255) * 4 + (row >> 8);
    float4 v = ((const float4*)src)[i];
    ushort4v o; o[0]=bf16c(v.x); o[1]=bf16c(v.y); o[2]=bf16c(v.z); o[3]=bf16c(v.w);
    *(ushort4v*)(dst + (size_t)orow * 256 + c4 * 4) = o;
  } else if (b < 2688) {
    int i = (b - 2560) * 256 + tid;            // 32768 f4
    float4 v = ((const float4*)we1)[i];
    ushort4v o; o[0]=bf16c(v.x); o[1]=bf16c(v.y); o[2]=bf16c(v.z); o[3]=bf16c(v.w);
    ((ushort4v*)we1o)[i] = o;
  } else if (b < 2694) {
    int i = (b - 2688) * 256 + tid;            // 1536 f4
    float4 v = ((const float4*)we2)[i];
    ushort4v o; o[0]=bf16c(v.x); o[1]=bf16c(v.y); o[2]=bf16c(v.z); o[3]=bf16c(v.w);
    ((ushort4v*)we2o)[i] = o;
  } else if (b < 3718) {
    int bb = b - 2694;
    int which = bb >> 8;
    const float* src = (which == 0) ? wh1f : (which == 1) ? wh1b
                     : (which == 2) ? wh2f : wh2b;
    unsigned char* dst = (which == 0) ? o8l1f : (which == 1) ? o8l1b
                       : (which == 2) ? o8l2f : o8l2b;
    int idx = (bb & 255) * 256 + tid;          // dword idx, [1024][64 dwords]
    int row = idx >> 6, k4 = (idx & 63) * 4;
    const float* r = src + (size_t)row * 256;
    unsigned o = 0;
#pragma unroll
    for (int j = 0; j < 4; ++j) {
      int kp = k4 + j;
      int u = (kp >> 6) + (kp & 63) * 4;       // inverse k-permute
      o |= ((unsigned)fp8c(r[u] * 64.0f)) << (8 * j);
    }
    ((unsigned*)dst)[idx] = o;
  } else if (b < 3726) {
    int m = (b - 3718) * 256 + tid;
    int dirq = m >> 10, mloc = m & 1023;
    int r = (mloc & 3) * 256 + (mloc >> 2);
    pb1[m] = dirq ? (b1bi[r] + b1bh[r]) : (b1fi[r] + b1fh[r]);
  } else {
    int m = (b - 3726) * 256 + tid;
    int dirq = m >> 10, mloc = m & 1023;
    int r = (mloc & 3) * 256 + (mloc >> 2);
    pb2[m] = dirq ? (b2bi[r] + b2bh[r]) : (b2fi[r] + b2fh[r]);
  }
}

// ---------------- ROI max pool -> rnn bf16 [t*32+n][c*2+ph] ----------------
__global__ __launch_bounds__(256) void roi_pool_kernel(
    const float* __restrict__ feat, const float* __restrict__ rois,
    unsigned short* __restrict__ rnn) {
  int n  = blockIdx.x;
  int cg = blockIdx.y;
  int tid = threadIdx.x;
  int pw = tid & 63, ph = (tid >> 6) & 1, cl = tid >> 7;
  int c = cg * 2 + cl;

  const float* r = rois + n * 5;
  int bi = (int)r[0];
  int x1 = (int)rintf(r[1] * (float)FW);
  int y1 = (int)rintf(r[2] * (float)FH);
  int x2 = (int)rintf(r[3] * (float)FW);
  int y2 = (int)rintf(r[4] * (float)FH);
  float rw = fmaxf((float)(x2 - x1 + 1), 1.0f);
  float rh = fmaxf((float)(y2 - y1 + 1), 1.0f);
  float bin_h = rh * 0.5f;
  float bin_w = rw * (1.0f / 64.0f);

  int hs = min(max((int)floorf((float)ph * bin_h) + y1, 0), FH);
  int he = min(max((int)ceilf((float)(ph + 1) * bin_h) + y1, 0), FH);
  int wst = min(max((int)floorf((float)pw * bin_w) + x1, 0), FW);
  int wen = min(max((int)ceilf((float)(pw + 1) * bin_w) + x1, 0), FW);

  float m = -1e30f;
  bool nonempty = (hs < he) && (wst < wen);
  const float* f = feat + ((size_t)bi * 512 + c) * (FH * FW);
  for (int h = hs; h < he; ++h) {
    const float* fr = f + h * FW;
    for (int w = wst; w < wen; ++w) m = fmaxf(m, fr[w]);
  }
  float out = nonempty ? m : 0.0f;
  rnn[((size_t)pw * NSEQ + n) * 1024 + c * 2 + ph] = bf16c(out);
}

// ---------------- bf16 MFMA GEMM ----------------
// mode 0: Cf[m*N+n] f32; mode 1: Cb[m*N+n] bf16;
// mode 5: xg write: A rows permuted (m = dir*1024 + unit*4 + gate); col = tn.
//   Cb[dir*2097152 + ((t*256+unit)*32+n)*4 + gate] = bf16((acc+pb[m])*1024), 8B quads.
#define GPITCH 40
__global__ __launch_bounds__(256) void gemm_bf16(
    const unsigned short* __restrict__ A, const unsigned short* __restrict__ B,
    float* __restrict__ Cf, unsigned short* __restrict__ Cb,
    int M, int N, int K,
    const float* __restrict__ bm1, const float* __restrict__ bn, int mode) {
  __shared__ unsigned short Al[128 * GPITCH];
  __shared__ unsigned short Bl[128 * GPITCH];
  int m0 = blockIdx.y * 128, n0 = blockIdx.x * 128;
  int tid = threadIdx.x;
  int wid = tid >> 6, l = tid & 63, ln15 = l & 15, kg = l >> 4;
  int wm = wid >> 1, wn = wid & 1;

  f32x4 acc[4][4];
#pragma unroll
  for (int i = 0; i < 4; ++i)
#pragma unroll
    for (int j = 0; j < 4; ++j)
#pragma unroll
      for (int q = 0; q < 4; ++q) acc[i][j][q] = 0.0f;

  for (int k0 = 0; k0 < K; k0 += 32) {
#pragma unroll
    for (int it = 0; it < 2; ++it) {
      int chunk = tid + it * 256;
      int row = chunk >> 2, part = chunk & 3;
      short8 va = *(const short8*)(A + (size_t)(m0 + row) * K + k0 + part * 8);
      *(short8*)(Al + row * GPITCH + part * 8) = va;
      short8 vb;
      if (n0 + row < N) {
        vb = *(const short8*)(B + (size_t)(n0 + row) * K + k0 + part * 8);
      } else {
#pragma unroll
        for (int q = 0; q < 8; ++q) vb[q] = 0;
      }
      *(short8*)(Bl + row * GPITCH + part * 8) = vb;
    }
    __syncthreads();

    short8 a[4], b[4];
#pragma unroll
    for (int mt = 0; mt < 4; ++mt)
      a[mt] = *(const short8*)(Al + (wm * 64 + mt * 16 + ln15) * GPITCH + kg * 8);
#pragma unroll
    for (int nt = 0; nt < 4; ++nt)
      b[nt] = *(const short8*)(Bl + (wn * 64 + nt * 16 + ln15) * GPITCH + kg * 8);
#pragma unroll
    for (int mt = 0; mt < 4; ++mt)
#pragma unroll
      for (int nt = 0; nt < 4; ++nt)
        acc[mt][nt] = __builtin_amdgcn_mfma_f32_16x16x32_bf16(a[mt], b[nt], acc[mt][nt], 0, 0, 0);
    __syncthreads();
  }

  if (mode == 5) {
#pragma unroll
    for (int mt = 0; mt < 4; ++mt) {
      int mbase = m0 + wm * 64 + mt * 16 + kg * 4;
      f32x4 pbv = *(const f32x4*)(bm1 + mbase);
      int dirq = mbase >> 10;
      int unit = (mbase & 1023) >> 2;
#pragma unroll
      for (int nt = 0; nt < 4; ++nt) {
        int col = n0 + wn * 64 + nt * 16 + ln15;
        int t = col >> 5, n = col & 31;
        ushort4v q;
#pragma unroll
        for (int j = 0; j < 4; ++j)
          q[j] = bf16c((acc[mt][nt][j] + pbv[j]) * 1024.0f);
        *(ushort4v*)(Cb + (size_t)dirq * 2097152u + ((t << 8) + unit) * 128 + n * 4) = q;
      }
    }
    return;
  }

#pragma unroll
  for (int mt = 0; mt < 4; ++mt) {
#pragma unroll
    for (int j = 0; j < 4; ++j) {
      int m = m0 + wm * 64 + mt * 16 + kg * 4 + j;
      float bmv = bm1 ? bm1[m] : 0.0f;
#pragma unroll
      for (int nt = 0; nt < 4; ++nt) {
        int n = n0 + wn * 64 + nt * 16 + ln15;
        if (n < N) {
          float v = acc[mt][nt][j] + bmv;
          if (bn) v += bn[n];
          if (mode == 1) Cb[(size_t)m * N + n] = bf16c(v);
          else Cf[(size_t)m * N + n] = v;
        }
      }
    }
  }
}

// ---------------- persistent BiLSTM layer v7: coalesced xg layout ----------------
// Grid 4 blocks: dir = blk>>1, batch-half = blk&1 (16 n). 512 thr = 8 waves.
// xg layout [dir][t][unit][n][gate]: lane's 8B quad -> 16 lanes read 128B
// contiguous (4 segments/load vs 16 before). Rest identical to R7.
__global__ __launch_bounds__(512, 2) void lstm_layer7(
    const unsigned short* __restrict__ xgb,  // see layout above; value = 1024*xg
    const unsigned char* __restrict__ w8fw,  // [1024][256] fp8 (x64), k-permuted
    const unsigned char* __restrict__ w8bw,
    unsigned short* __restrict__ hcatb) {    // [64][32][512] bf16
  const int dir = blockIdx.x >> 1;
  const int nbase = (blockIdx.x & 1) * 16;
  const int tid = threadIdx.x;
  const int w = tid >> 6;
  const int l = tid & 63;
  const int ln15 = l & 15;
  const int kg = l >> 4;
  const int u_wave = w * 32;

  __shared__ unsigned char h8[2][16][256];    // fp8 h (x16), k-permuted + swizzled
  __shared__ unsigned short hx[2][256][18];   // bf16 h staging for hcat

  const unsigned char* W8 = dir ? w8bw : w8fw;

  unsigned long long afrag[8][8];
  {
    int gate = ln15 & 3, du = ln15 >> 2;
#pragma unroll
    for (int mt = 0; mt < 8; ++mt) {
      const unsigned char* wr = W8 + (size_t)((gate << 8) + u_wave + mt * 4 + du) * 256;
#pragma unroll
      for (int kc = 0; kc < 8; ++kc)
        afrag[mt][kc] = *(const unsigned long long*)(wr + kc * 32 + kg * 8);
    }
  }

  const unsigned short* xgd = xgb + (size_t)dir * 2097152u;
  const int lane_off = (nbase + ln15) * 4;    // n*4 u16 within [unit] row
  float cst[8] = {0.f, 0.f, 0.f, 0.f, 0.f, 0.f, 0.f, 0.f};
  f32x4 acc[8];
  ushort4v xnext[8];

  {
    int t0 = dir ? 63 : 0;
    const unsigned short* xb = xgd + (size_t)t0 * 32768 + lane_off;
#pragma unroll
    for (int mt = 0; mt < 8; ++mt)
      xnext[mt] = *(const ushort4v*)(xb + (u_wave + mt * 4 + kg) * 128);
#pragma unroll
    for (int mt = 0; mt < 8; ++mt)
#pragma unroll
      for (int j = 0; j < 4; ++j) acc[mt][j] = b2f(xnext[mt][j]);
  }

  const int swzw = (ln15 & 7) << 4;
  const int myslot = kg * 64 + w * 8;
  const float kNI = -1.0f / 1024.0f;
  const float kP2 = 2.0f / 1024.0f;

  for (int s = 0; s < TSTEPS; ++s) {
    const int t = dir ? (63 - s) : s;
    const int p = s & 1;

    // A) issue next-step xg loads first (4-segment coalesced)
    if (s < TSTEPS - 1) {
      int tn2 = dir ? (t - 1) : (t + 1);
      const unsigned short* xb = xgd + (size_t)tn2 * 32768 + lane_off;
#pragma unroll
      for (int mt = 0; mt < 8; ++mt)
        xnext[mt] = *(const ushort4v*)(xb + (u_wave + mt * 4 + kg) * 128);
    }

    // B) MFMA
    if (s > 0) {
      const unsigned char* hrow = &h8[p][ln15][0];
#pragma unroll
      for (int kc = 0; kc < 8; ++kc) {
        unsigned long long hb =
            *(const unsigned long long*)(hrow + ((kc * 32 + kg * 8) ^ swzw));
#pragma unroll
        for (int mt = 0; mt < 8; ++mt)
          acc[mt] = __builtin_amdgcn_mfma_f32_16x16x32_fp8_fp8(
              (long)afrag[mt][kc], (long)hb, acc[mt], 0, 0, 0);
      }
    }

    // C) cell
    {
      float hv[8];
#pragma unroll
      for (int mt = 0; mt < 8; ++mt) {
        float gi = __builtin_amdgcn_rcpf(1.0f + __expf(acc[mt][0] * kNI));
        float gf = __builtin_amdgcn_rcpf(1.0f + __expf(acc[mt][1] * kNI));
        float gg = 1.0f - 2.0f * __builtin_amdgcn_rcpf(1.0f + __expf(acc[mt][2] * kP2));
        float go = __builtin_amdgcn_rcpf(1.0f + __expf(acc[mt][3] * kNI));
        float c = gf * cst[mt] + gi * gg;
        cst[mt] = c;
        float h = go * (1.0f - 2.0f * __builtin_amdgcn_rcpf(1.0f + __expf(2.0f * c)));
        hv[mt] = h;
        hx[p ^ 1][u_wave + mt * 4 + kg][ln15] = bf16c(h);
      }
      unsigned d0 = pk4_fp8(hv[0] * 16.f, hv[1] * 16.f, hv[2] * 16.f, hv[3] * 16.f);
      unsigned d1 = pk4_fp8(hv[4] * 16.f, hv[5] * 16.f, hv[6] * 16.f, hv[7] * 16.f);
      unsigned long long pk = (unsigned long long)d0 | ((unsigned long long)d1 << 32);
      *(unsigned long long*)(&h8[p ^ 1][ln15][0] + (myslot ^ swzw)) = pk;

      if (s < TSTEPS - 1) {
#pragma unroll
        for (int mt = 0; mt < 8; ++mt)
#pragma unroll
          for (int j = 0; j < 4; ++j) acc[mt][j] = b2f(xnext[mt][j]);
      }
    }

    __syncthreads();

    // D) coalesced hcat write
    {
      int n_loc = tid >> 5;
      int u0 = (tid & 31) * 8;
      short8 v;
#pragma unroll
      for (int q = 0; q < 8; ++q) v[q] = (short)hx[p ^ 1][u0 + q][n_loc];
      *(short8*)(hcatb + ((size_t)t * NSEQ + nbase + n_loc) * 512 + dir * 256 + u0) = v;
    }
  }
}

// ---------------- fused log-softmax + CTC loss ----------------
#define CTC_S 17
__global__ __launch_bounds__(576) void ctc_kernel(
    const float* __restrict__ preds,   // [64][32][12]
    const int* __restrict__ text,      // [256]
    const int* __restrict__ text_len,  // [32]
    float* __restrict__ out) {
  __shared__ float alpha[NSEQ][CTC_S];
  __shared__ float nalpha[NSEQ][CTC_S];
  __shared__ float lse[NSEQ];
  __shared__ int ext[NSEQ][CTC_S];
  __shared__ unsigned char allow[NSEQ][CTC_S];
  __shared__ unsigned char validm[NSEQ][CTC_S];
  __shared__ int tlsh[NSEQ];
  __shared__ float logp_sh[NSEQ];

  int tid = threadIdx.x;
  int b = tid & 31, sIdx = tid >> 5;
  bool active = sIdx < CTC_S;

  if (tid < NSEQ) tlsh[tid] = text_len[tid];
  __syncthreads();

  if (active) {
    int tl = tlsh[b];
    int off = 0;
    for (int i = 0; i < b; ++i) off += tlsh[i];
    int e = 0;
    if (sIdx & 1) {
      int lbl = (sIdx - 1) >> 1;
      int idx = off + lbl;
      if (idx > 255) idx = 255;
      e = (lbl < tl) ? text[idx] : 0;
    }
    ext[b][sIdx] = e;
    validm[b][sIdx] = (sIdx < 2 * tl + 1) ? 1 : 0;
  }
  __syncthreads();
  if (active) {
    int e = ext[b][sIdx];
    bool same2 = (sIdx >= 2) && (e == ext[b][sIdx - 2]);
    allow[b][sIdx] = ((sIdx >= 2) && (e != 0) && !same2) ? 1 : 0;
  }
  if (tid < NSEQ) {
    const float* p = preds + (size_t)b * 12;
    float mx = p[0];
    for (int k = 1; k < 12; ++k) mx = fmaxf(mx, p[k]);
    float ssum = 0.f;
    for (int k = 0; k < 12; ++k) ssum += expf(p[k] - mx);
    lse[b] = mx + logf(ssum);
  }
  __syncthreads();
  if (active) {
    float a = -1e30f;
    if (sIdx == 0) a = preds[(size_t)b * 12 + 0] - lse[b];
    else if (sIdx == 1 && tlsh[b] > 0) a = preds[(size_t)b * 12 + ext[b][1]] - lse[b];
    alpha[b][sIdx] = a;
  }
  __syncthreads();

  for (int t = 1; t < TSTEPS; ++t) {
    if (tid < NSEQ) {
      const float* p = preds + ((size_t)t * NSEQ + b) * 12;
      float mx = p[0];
      for (int k = 1; k < 12; ++k) mx = fmaxf(mx, p[k]);
      float ssum = 0.f;
      for (int k = 0; k < 12; ++k) ssum += expf(p[k] - mx);
      lse[b] = mx + logf(ssum);
    }
    __syncthreads();
    if (active) {
      float a = alpha[b][sIdx];
      float a1 = (sIdx >= 1) ? alpha[b][sIdx - 1] : -1e30f;
      float a2 = (sIdx >= 2 && allow[b][sIdx]) ? alpha[b][sIdx - 2] : -1e30f;
      float m = fmaxf(a, fmaxf(a1, a2));
      float ssum = expf(a - m) + expf(a1 - m) + expf(a2 - m);
      float emit = preds[((size_t)t * NSEQ + b) * 12 + ext[b][sIdx]] - lse[b];
      float nv = m + logf(ssum) + emit;
      nalpha[b][sIdx] = validm[b][sIdx] ? nv : -1e30f;
    }
    __syncthreads();
    if (active) alpha[b][sIdx] = nalpha[b][sIdx];
    __syncthreads();
  }

  if (tid < NSEQ) {
    int tl = tlsh[b];
    float a1 = alpha[b][2 * tl];
    float a2 = (tl > 0) ? alpha[b][2 * tl - 1] : -1e30f;
    float m = fmaxf(a1, a2);
    logp_sh[b] = m + logf(expf(a1 - m) + expf(a2 - m));
  }
  __syncthreads();
  if (tid == 0) {
    float ssum = 0.f;
    for (int i = 0; i < NSEQ; ++i) ssum += logp_sh[i];
    out[0] = -ssum / (float)NSEQ;
  }
}

// ---------------- launch ----------------
extern "C" void kernel_launch(void* const* d_in, const int* in_sizes, int n_in,
                              void* d_out, int out_size, void* d_ws, size_t ws_size,
                              hipStream_t stream) {
  (void)in_sizes; (void)n_in; (void)out_size; (void)ws_size;
  const float* base_feat = (const float*)d_in[0];
  const int* text = (const int*)d_in[1];
  const int* text_len = (const int*)d_in[2];
  const float* rois = (const float*)d_in[3];
  const float* l1_fw_W_ih = (const float*)d_in[4];
  const float* l1_fw_W_hh = (const float*)d_in[5];
  const float* l1_fw_b_ih = (const float*)d_in[6];
  const float* l1_fw_b_hh = (const float*)d_in[7];
  const float* l1_bw_W_ih = (const float*)d_in[8];
  const float* l1_bw_W_hh = (const float*)d_in[9];
  const float* l1_bw_b_ih = (const float*)d_in[10];
  const float* l1_bw_b_hh = (const float*)d_in[11];
  const float* l2_fw_W_ih = (const float*)d_in[12];
  const float* l2_fw_W_hh = (const float*)d_in[13];
  const float* l2_fw_b_ih = (const float*)d_in[14];
  const float* l2_fw_b_hh = (const float*)d_in[15];
  const float* l2_bw_W_ih = (const float*)d_in[16];
  const float* l2_bw_W_hh = (const float*)d_in[17];
  const float* l2_bw_b_ih = (const float*)d_in[18];
  const float* l2_bw_b_hh = (const float*)d_in[19];
  const float* W_emb1 = (const float*)d_in[20];
  const float* b_emb1 = (const float*)d_in[21];
  const float* W_emb2 = (const float*)d_in[22];
  const float* b_emb2 = (const float*)d_in[23];

  float* ws = (float*)d_ws;
  unsigned short* xgb  = (unsigned short*)(ws + OFF_XGB);
  unsigned short* rnnb = (unsigned short*)(ws + OFF_RNNB);
  unsigned short* w12b = (unsigned short*)(ws + OFF_W12B);
  unsigned short* w22b = (unsigned short*)(ws + OFF_W22B);
  unsigned short* we1b = (unsigned short*)(ws + OFF_WE1B);
  unsigned short* we2b = (unsigned short*)(ws + OFF_WE2B);
  float* pb1 = ws + OFF_PB1;
  float* pb2 = ws + OFF_PB2;
  unsigned char* w8l1f = (unsigned char*)(ws + OFF_W8L1F);
  unsigned char* w8l1b = (unsigned char*)(ws + OFF_W8L1B);
  unsigned char* w8l2f = (unsigned char*)(ws + OFF_W8L2F);
  unsigned char* w8l2b = (unsigned char*)(ws + OFF_W8L2B);
  unsigned short* hcb1 = (unsigned short*)(ws + OFF_HCB1);
  unsigned short* hcb2 = (unsigned short*)(ws + OFF_HCB2);
  unsigned short* h1b  = (unsigned short*)(ws + OFF_H1B);
  float* preds = ws + OFF_PREDS;

  // 0) all weight/bias prep in one launch
  prep_kernel<<<3734, 256, 0, stream>>>(
      l1_fw_W_ih, l1_bw_W_ih, l2_fw_W_ih, l2_bw_W_ih, W_emb1, W_emb2,
      l1_fw_W_hh, l1_bw_W_hh, l2_fw_W_hh, l2_bw_W_hh,
      l1_fw_b_ih, l1_fw_b_hh, l1_bw_b_ih, l1_bw_b_hh,
      l2_fw_b_ih, l2_fw_b_hh, l2_bw_b_ih, l2_bw_b_hh,
      w12b, w22b, we1b, we2b, w8l1f, w8l1b, w8l2f, w8l2b, pb1, pb2);

  // 1) ROI max pool -> rnn bf16 [2048][1024]
  roi_pool_kernel<<<dim3(32, 256), 256, 0, stream>>>(base_feat, rois, rnnb);

  // 2) xg layer1, both dirs in one launch (mode 5)
  gemm_bf16<<<dim3(16, 16), 256, 0, stream>>>(w12b, rnnb, nullptr, xgb,
      2048, 2048, 1024, pb1, nullptr, 5);

  // 3) layer-1 recurrence
  lstm_layer7<<<4, 512, 0, stream>>>(xgb, w8l1f, w8l1b, hcb1);

  // 4) h1 = hcat1 @ W_emb1^T + b_emb1 -> bf16 [2048][256]
  gemm_bf16<<<dim3(2, 16), 256, 0, stream>>>(hcb1, we1b, nullptr, h1b,
      2048, 256, 512, nullptr, b_emb1, 1);

  // 5) xg layer2 (mode 5)
  gemm_bf16<<<dim3(16, 16), 256, 0, stream>>>(w22b, h1b, nullptr, xgb,
      2048, 2048, 256, pb2, nullptr, 5);

  // 6) layer-2 recurrence
  lstm_layer7<<<4, 512, 0, stream>>>(xgb, w8l2f, w8l2b, hcb2);

  // 7) preds = hcat2 @ W_emb2^T + b_emb2 (f32, N=12 guarded)
  gemm_bf16<<<dim3(1, 16), 256, 0, stream>>>(hcb2, we2b, preds, nullptr,
      2048, 12, 512, nullptr, b_emb2, 0);

  // 8) log-softmax + CTC
  ctc_kernel<<<1, 576, 0, stream>>>(preds, text, text_len, (float*)d_out);
}

// Round 9
// 458.993 us; speedup vs baseline: 4.3778x; 1.1915x over previous
//
#include <hip/hip_runtime.h>
#include <math.h>

// ---------------- problem constants ----------------
#define TSTEPS 64
#define NSEQ   32
#define FH     40
#define FW     160

// ---------------- workspace layout (float units) ----------------
#define OFF_XGB    0u            // [2][64 t][256 unit][32 n][4 gate] bf16, x1024
#define OFF_RNNB   2097152u      // [2048 tn][1024] bf16
#define OFF_W12B   3145728u      // W_ih l1 bf16, row-permuted unit*4+gate, [2048][1024]
#define OFF_W22B   4194304u      // W_ih l2 bf16 permuted [2048][256]
#define OFF_WE1B   4456448u      // W_emb1 bf16 [256][512], COLUMNS pi-permuted
#define OFF_WE2B   4521984u      // W_emb2 bf16 [12][512], COLUMNS pi-permuted
#define OFF_PB1    4525056u      // combined permuted bias l1 [2048] f32
#define OFF_PB2    4527104u      // combined permuted bias l2 [2048] f32
#define OFF_W8L1F  4529152u      // W_hh fp8 (x64) k-permuted [1024][256]
#define OFF_W8L1B  4594688u
#define OFF_W8L2F  4660224u
#define OFF_W8L2B  4725760u
#define OFF_HCB1   4791296u      // hcat1 bf16 [2048][512] (pi-permuted cols)
#define OFF_HCB2   5315584u
#define OFF_H1B    5839872u      // h1 bf16 [2048][256]
#define OFF_PREDS  6102016u      // [2048][12] f32

typedef __attribute__((ext_vector_type(8))) short short8;
typedef __attribute__((ext_vector_type(4))) float f32x4;
typedef __attribute__((ext_vector_type(4))) unsigned short ushort4v;
typedef __attribute__((ext_vector_type(4))) unsigned uint4v;

static __device__ inline unsigned short bf16c(float x) {
  union { float f; unsigned u; } v; v.f = x;
  unsigned r = v.u + 0x7fff + ((v.u >> 16) & 1);   // RNE
  return (unsigned short)(r >> 16);
}
static __device__ inline float b2f(unsigned short u) {
  union { unsigned u; float f; } v; v.u = ((unsigned)u) << 16;
  return v.f;
}
// pack 2 f32 -> u32 of 2 bf16 (hardware cvt_pk, RNE)
static __device__ inline unsigned pk_bf16(float lo, float hi) {
  unsigned r;
  asm("v_cvt_pk_bf16_f32 %0, %1, %2" : "=v"(r) : "v"(lo), "v"(hi));
  return r;
}
// f32 -> fp8 e4m3fn (OCP): RNE, saturate, flush subnormals
static __device__ inline unsigned char fp8c(float x) {
  union { float f; unsigned u; } v; v.f = x;
  unsigned s = (v.u >> 24) & 0x80;
  float ax = fabsf(x);
  if (ax < 0.015625f) return (unsigned char)s;
  if (ax >= 448.0f) return (unsigned char)(s | 0x7e);
  unsigned e = (v.u >> 23) & 0xff;
  unsigned m = v.u & 0x7fffff;
  unsigned r = m + 0x7ffff + ((m >> 20) & 1);
  if (r >> 23) { e += 1; r = 0; }
  unsigned m3 = (r >> 20) & 7;
  int ee = (int)e - 127 + 7;
  if (ee > 15) return (unsigned char)(s | 0x7e);
  return (unsigned char)(s | (ee << 3) | m3);
}
static __device__ inline unsigned pk4_fp8(float a, float b, float c, float d) {
#if __has_builtin(__builtin_amdgcn_cvt_pk_fp8_f32)
  int r = __builtin_amdgcn_cvt_pk_fp8_f32(a, b, 0, false);
  r = __builtin_amdgcn_cvt_pk_fp8_f32(c, d, r, true);
  return (unsigned)r;
#else
  return (unsigned)fp8c(a) | ((unsigned)fp8c(b) << 8)
       | ((unsigned)fp8c(c) << 16) | ((unsigned)fp8c(d) << 24);
#endif
}

// ---------------- single prep kernel ----------------
// blocks: [0,2048) l1 W_ih bf16 perm | [2048,2560) l2 W_ih | [2560,2688) we1 pi-col |
// [2688,2694) we2 pi-col | [2694,3718) fp8 W_hh x4 | [3718,3726) pb1 | [3726,3734) pb2
__global__ __launch_bounds__(256) void prep_kernel(
    const float* __restrict__ w1f, const float* __restrict__ w1b,
    const float* __restrict__ w2f, const float* __restrict__ w2b,
    const float* __restrict__ we1, const float* __restrict__ we2,
    const float* __restrict__ wh1f, const float* __restrict__ wh1b,
    const float* __restrict__ wh2f, const float* __restrict__ wh2b,
    const float* __restrict__ b1fi, const float* __restrict__ b1fh,
    const float* __restrict__ b1bi, const float* __restrict__ b1bh,
    const float* __restrict__ b2fi, const float* __restrict__ b2fh,
    const float* __restrict__ b2bi, const float* __restrict__ b2bh,
    unsigned short* __restrict__ w12b, unsigned short* __restrict__ w22b,
    unsigned short* __restrict__ we1o, unsigned short* __restrict__ we2o,
    unsigned char* __restrict__ o8l1f, unsigned char* __restrict__ o8l1b,
    unsigned char* __restrict__ o8l2f, unsigned char* __restrict__ o8l2b,
    float* __restrict__ pb1, float* __restrict__ pb2) {
  int b = blockIdx.x, tid = threadIdx.x;
  if (b < 2048) {
    const float* src = (b < 1024) ? w1f : w1b;
    unsigned short* dst = w12b + (size_t)((b < 1024) ? 0 : 1048576);
    int i = (b & 1023) * 256 + tid;
    int row = i >> 8, c4 = i & 255;
    int orow = (row & 255) * 4 + (row >> 8);   // gate*256+unit -> unit*4+gate
    float4 v = ((const float4*)src)[i];
    ushort4v o; o[0]=bf16c(v.x); o[1]=bf16c(v.y); o[2]=bf16c(v.z); o[3]=bf16c(v.w);
    *(ushort4v*)(dst + (size_t)orow * 1024 + c4 * 4) = o;
  } else if (b < 2560) {
    int bb = b - 2048;
    const float* src = (bb < 256) ? w2f : w2b;
    unsigned short* dst = w22b + (size_t)((bb < 256) ? 0 : 262144);
    int i = (bb & 255) * 256 + tid;
    int row = i >> 6, c4 = i & 63;
    int orow = (row & 255) * 4 + (row >> 8);
    float4 v = ((const float4*)src)[i];
    ushort4v o; o[0]=bf16c(v.x); o[1]=bf16c(v.y); o[2]=bf16c(v.z); o[3]=bf16c(v.w);
    *(ushort4v*)(dst + (size_t)orow * 256 + c4 * 4) = o;
  } else if (b < 2688) {
    // we1: out[j][d*256 + k] = in[j][d*256 + invpi(k)], invpi(k) = (k>>6) + (k&63)*4
    int i = (b - 2560) * 256 + tid;            // 0..32767 output quads
    int j = i >> 7, c4 = (i & 127) * 4;
    ushort4v o;
#pragma unroll
    for (int q = 0; q < 4; ++q) {
      int c = c4 + q;
      int d = c >> 8, k = c & 255;
      int u = (k >> 6) + (k & 63) * 4;
      o[q] = bf16c(we1[(size_t)j * 512 + d * 256 + u]);
    }
    ((ushort4v*)we1o)[i] = o;
  } else if (b < 2694) {
    int i = (b - 2688) * 256 + tid;            // 0..1535 quads (12x512)
    int j = i >> 7, c4 = (i & 127) * 4;
    ushort4v o;
#pragma unroll
    for (int q = 0; q < 4; ++q) {
      int c = c4 + q;
      int d = c >> 8, k = c & 255;
      int u = (k >> 6) + (k & 63) * 4;
      o[q] = bf16c(we2[(size_t)j * 512 + d * 256 + u]);
    }
    ((ushort4v*)we2o)[i] = o;
  } else if (b < 3718) {
    int bb = b - 2694;
    int which = bb >> 8;
    const float* src = (which == 0) ? wh1f : (which == 1) ? wh1b
                     : (which == 2) ? wh2f : wh2b;
    unsigned char* dst = (which == 0) ? o8l1f : (which == 1) ? o8l1b
                       : (which == 2) ? o8l2f : o8l2b;
    int idx = (bb & 255) * 256 + tid;
    int row = idx >> 6, k4 = (idx & 63) * 4;
    const float* r = src + (size_t)row * 256;
    unsigned o = 0;
#pragma unroll
    for (int j = 0; j < 4; ++j) {
      int kp = k4 + j;
      int u = (kp >> 6) + (kp & 63) * 4;       // inverse k-permute
      o |= ((unsigned)fp8c(r[u] * 64.0f)) << (8 * j);
    }
    ((unsigned*)dst)[idx] = o;
  } else if (b < 3726) {
    int m = (b - 3718) * 256 + tid;
    int dirq = m >> 10, mloc = m & 1023;
    int r = (mloc & 3) * 256 + (mloc >> 2);
    pb1[m] = dirq ? (b1bi[r] + b1bh[r]) : (b1fi[r] + b1fh[r]);
  } else {
    int m = (b - 3726) * 256 + tid;
    int dirq = m >> 10, mloc = m & 1023;
    int r = (mloc & 3) * 256 + (mloc >> 2);
    pb2[m] = dirq ? (b2bi[r] + b2bh[r]) : (b2fi[r] + b2fh[r]);
  }
}

// ---------------- ROI max pool -> rnn bf16 [t*32+n][c*2+ph] ----------------
__global__ __launch_bounds__(256) void roi_pool_kernel(
    const float* __restrict__ feat, const float* __restrict__ rois,
    unsigned short* __restrict__ rnn) {
  int n  = blockIdx.x;
  int cg = blockIdx.y;
  int tid = threadIdx.x;
  int pw = tid & 63, ph = (tid >> 6) & 1, cl = tid >> 7;
  int c = cg * 2 + cl;

  const float* r = rois + n * 5;
  int bi = (int)r[0];
  int x1 = (int)rintf(r[1] * (float)FW);
  int y1 = (int)rintf(r[2] * (float)FH);
  int x2 = (int)rintf(r[3] * (float)FW);
  int y2 = (int)rintf(r[4] * (float)FH);
  float rw = fmaxf((float)(x2 - x1 + 1), 1.0f);
  float rh = fmaxf((float)(y2 - y1 + 1), 1.0f);
  float bin_h = rh * 0.5f;
  float bin_w = rw * (1.0f / 64.0f);

  int hs = min(max((int)floorf((float)ph * bin_h) + y1, 0), FH);
  int he = min(max((int)ceilf((float)(ph + 1) * bin_h) + y1, 0), FH);
  int wst = min(max((int)floorf((float)pw * bin_w) + x1, 0), FW);
  int wen = min(max((int)ceilf((float)(pw + 1) * bin_w) + x1, 0), FW);

  float m = -1e30f;
  bool nonempty = (hs < he) && (wst < wen);
  const float* f = feat + ((size_t)bi * 512 + c) * (FH * FW);
  for (int h = hs; h < he; ++h) {
    const float* fr = f + h * FW;
    for (int w = wst; w < wen; ++w) m = fmaxf(m, fr[w]);
  }
  float out = nonempty ? m : 0.0f;
  rnn[((size_t)pw * NSEQ + n) * 1024 + c * 2 + ph] = bf16c(out);
}

// ---------------- bf16 MFMA GEMM ----------------
// mode 0: Cf[m*N+n] f32; mode 1: Cb[m*N+n] bf16;
// mode 5: xg write: Cb[dir*2097152 + ((t*256+unit)*32+n)*4 + gate] = bf16(v*1024)
#define GPITCH 40
__global__ __launch_bounds__(256) void gemm_bf16(
    const unsigned short* __restrict__ A, const unsigned short* __restrict__ B,
    float* __restrict__ Cf, unsigned short* __restrict__ Cb,
    int M, int N, int K,
    const float* __restrict__ bm1, const float* __restrict__ bn, int mode) {
  __shared__ unsigned short Al[128 * GPITCH];
  __shared__ unsigned short Bl[128 * GPITCH];
  int m0 = blockIdx.y * 128, n0 = blockIdx.x * 128;
  int tid = threadIdx.x;
  int wid = tid >> 6, l = tid & 63, ln15 = l & 15, kg = l >> 4;
  int wm = wid >> 1, wn = wid & 1;

  f32x4 acc[4][4];
#pragma unroll
  for (int i = 0; i < 4; ++i)
#pragma unroll
    for (int j = 0; j < 4; ++j)
#pragma unroll
      for (int q = 0; q < 4; ++q) acc[i][j][q] = 0.0f;

  for (int k0 = 0; k0 < K; k0 += 32) {
#pragma unroll
    for (int it = 0; it < 2; ++it) {
      int chunk = tid + it * 256;
      int row = chunk >> 2, part = chunk & 3;
      short8 va = *(const short8*)(A + (size_t)(m0 + row) * K + k0 + part * 8);
      *(short8*)(Al + row * GPITCH + part * 8) = va;
      short8 vb;
      if (n0 + row < N) {
        vb = *(const short8*)(B + (size_t)(n0 + row) * K + k0 + part * 8);
      } else {
#pragma unroll
        for (int q = 0; q < 8; ++q) vb[q] = 0;
      }
      *(short8*)(Bl + row * GPITCH + part * 8) = vb;
    }
    __syncthreads();

    short8 a[4], b[4];
#pragma unroll
    for (int mt = 0; mt < 4; ++mt)
      a[mt] = *(const short8*)(Al + (wm * 64 + mt * 16 + ln15) * GPITCH + kg * 8);
#pragma unroll
    for (int nt = 0; nt < 4; ++nt)
      b[nt] = *(const short8*)(Bl + (wn * 64 + nt * 16 + ln15) * GPITCH + kg * 8);
#pragma unroll
    for (int mt = 0; mt < 4; ++mt)
#pragma unroll
      for (int nt = 0; nt < 4; ++nt)
        acc[mt][nt] = __builtin_amdgcn_mfma_f32_16x16x32_bf16(a[mt], b[nt], acc[mt][nt], 0, 0, 0);
    __syncthreads();
  }

  if (mode == 5) {
#pragma unroll
    for (int mt = 0; mt < 4; ++mt) {
      int mbase = m0 + wm * 64 + mt * 16 + kg * 4;
      f32x4 pbv = *(const f32x4*)(bm1 + mbase);
      int dirq = mbase >> 10;
      int unit = (mbase & 1023) >> 2;
#pragma unroll
      for (int nt = 0; nt < 4; ++nt) {
        int col = n0 + wn * 64 + nt * 16 + ln15;
        int t = col >> 5, n = col & 31;
        ushort4v q;
#pragma unroll
        for (int j = 0; j < 4; ++j)
          q[j] = bf16c((acc[mt][nt][j] + pbv[j]) * 1024.0f);
        *(ushort4v*)(Cb + (size_t)dirq * 2097152u + ((t << 8) + unit) * 128 + n * 4) = q;
      }
    }
    return;
  }

#pragma unroll
  for (int mt = 0; mt < 4; ++mt) {
#pragma unroll
    for (int j = 0; j < 4; ++j) {
      int m = m0 + wm * 64 + mt * 16 + kg * 4 + j;
      float bmv = bm1 ? bm1[m] : 0.0f;
#pragma unroll
      for (int nt = 0; nt < 4; ++nt) {
        int n = n0 + wn * 64 + nt * 16 + ln15;
        if (n < N) {
          float v = acc[mt][nt][j] + bmv;
          if (bn) v += bn[n];
          if (mode == 1) Cb[(size_t)m * N + n] = bf16c(v);
          else Cf[(size_t)m * N + n] = v;
        }
      }
    }
  }
}

// ---------------- persistent BiLSTM layer v8: direct pi-permuted hcat store ------
// Grid 4 blocks: dir = blk>>1, batch-half = blk&1 (16 n). 512 thr = 8 waves.
// Cell writes hcat DIRECTLY (one short8/lane at pi-slot kg*64+w*8, contiguous over
// mt) -- no hx staging, no post-barrier phase. Downstream W_emb cols pi-permuted.
__global__ __launch_bounds__(512, 2) void lstm_layer8(
    const unsigned short* __restrict__ xgb,  // [dir][t][unit][n][gate] bf16, x1024
    const unsigned char* __restrict__ w8fw,  // [1024][256] fp8 (x64), k-permuted
    const unsigned char* __restrict__ w8bw,
    unsigned short* __restrict__ hcatb) {    // [64][32][512] bf16, pi-cols
  const int dir = blockIdx.x >> 1;
  const int nbase = (blockIdx.x & 1) * 16;
  const int tid = threadIdx.x;
  const int w = tid >> 6;
  const int l = tid & 63;
  const int ln15 = l & 15;
  const int kg = l >> 4;
  const int u_wave = w * 32;

  __shared__ unsigned char h8[2][16][256];    // fp8 h (x16), k-permuted + swizzled

  const unsigned char* W8 = dir ? w8bw : w8fw;

  unsigned long long afrag[8][8];
  {
    int gate = ln15 & 3, du = ln15 >> 2;
#pragma unroll
    for (int mt = 0; mt < 8; ++mt) {
      const unsigned char* wr = W8 + (size_t)((gate << 8) + u_wave + mt * 4 + du) * 256;
#pragma unroll
      for (int kc = 0; kc < 8; ++kc)
        afrag[mt][kc] = *(const unsigned long long*)(wr + kc * 32 + kg * 8);
    }
  }

  const unsigned short* xgd = xgb + (size_t)dir * 2097152u;
  const int lane_off = (nbase + ln15) * 4;
  float cst[8] = {0.f, 0.f, 0.f, 0.f, 0.f, 0.f, 0.f, 0.f};
  f32x4 acc[8];
  ushort4v xnext[8];

  {
    int t0 = dir ? 63 : 0;
    const unsigned short* xb = xgd + (size_t)t0 * 32768 + lane_off;
#pragma unroll
    for (int mt = 0; mt < 8; ++mt)
      xnext[mt] = *(const ushort4v*)(xb + (u_wave + mt * 4 + kg) * 128);
#pragma unroll
    for (int mt = 0; mt < 8; ++mt)
#pragma unroll
      for (int j = 0; j < 4; ++j) acc[mt][j] = b2f(xnext[mt][j]);
  }

  const int swzw = (ln15 & 7) << 4;
  const int myslot = kg * 64 + w * 8;        // pi-slot of this lane's 8 h values
  const float kNI = -1.0f / 1024.0f;
  const float kP2 = 2.0f / 1024.0f;

  for (int s = 0; s < TSTEPS; ++s) {
    const int t = dir ? (63 - s) : s;
    const int p = s & 1;

    // A) issue next-step xg loads first
    if (s < TSTEPS - 1) {
      int tn2 = dir ? (t - 1) : (t + 1);
      const unsigned short* xb = xgd + (size_t)tn2 * 32768 + lane_off;
#pragma unroll
      for (int mt = 0; mt < 8; ++mt)
        xnext[mt] = *(const ushort4v*)(xb + (u_wave + mt * 4 + kg) * 128);
    }

    // B) MFMA
    if (s > 0) {
      const unsigned char* hrow = &h8[p][ln15][0];
#pragma unroll
      for (int kc = 0; kc < 8; ++kc) {
        unsigned long long hb =
            *(const unsigned long long*)(hrow + ((kc * 32 + kg * 8) ^ swzw));
#pragma unroll
        for (int mt = 0; mt < 8; ++mt)
          acc[mt] = __builtin_amdgcn_mfma_f32_16x16x32_fp8_fp8(
              (long)afrag[mt][kc], (long)hb, acc[mt], 0, 0, 0);
      }
    }

    // C) cell + fp8 LDS write + DIRECT bf16 hcat store
    {
      float hv[8];
#pragma unroll
      for (int mt = 0; mt < 8; ++mt) {
        float gi = __builtin_amdgcn_rcpf(1.0f + __expf(acc[mt][0] * kNI));
        float gf = __builtin_amdgcn_rcpf(1.0f + __expf(acc[mt][1] * kNI));
        float gg = 1.0f - 2.0f * __builtin_amdgcn_rcpf(1.0f + __expf(acc[mt][2] * kP2));
        float go = __builtin_amdgcn_rcpf(1.0f + __expf(acc[mt][3] * kNI));
        float c = gf * cst[mt] + gi * gg;
        cst[mt] = c;
        hv[mt] = go * (1.0f - 2.0f * __builtin_amdgcn_rcpf(1.0f + __expf(2.0f * c)));
      }
      unsigned d0 = pk4_fp8(hv[0] * 16.f, hv[1] * 16.f, hv[2] * 16.f, hv[3] * 16.f);
      unsigned d1 = pk4_fp8(hv[4] * 16.f, hv[5] * 16.f, hv[6] * 16.f, hv[7] * 16.f);
      unsigned long long pk = (unsigned long long)d0 | ((unsigned long long)d1 << 32);
      *(unsigned long long*)(&h8[p ^ 1][ln15][0] + (myslot ^ swzw)) = pk;

      uint4v hb16;
      hb16[0] = pk_bf16(hv[0], hv[1]);
      hb16[1] = pk_bf16(hv[2], hv[3]);
      hb16[2] = pk_bf16(hv[4], hv[5]);
      hb16[3] = pk_bf16(hv[6], hv[7]);
      *(uint4v*)(hcatb + ((size_t)t * NSEQ + nbase + ln15) * 512 + dir * 256 + myslot) = hb16;

      if (s < TSTEPS - 1) {
#pragma unroll
        for (int mt = 0; mt < 8; ++mt)
#pragma unroll
          for (int j = 0; j < 4; ++j) acc[mt][j] = b2f(xnext[mt][j]);
      }
    }

    __syncthreads();
  }
}

// ---------------- fused log-softmax + CTC loss (parallel lp precompute) ----------
#define CTC_S 17
__global__ __launch_bounds__(576) void ctc_kernel(
    const float* __restrict__ preds,   // [64][32][12]
    const int* __restrict__ text,      // [256]
    const int* __restrict__ text_len,  // [32]
    float* __restrict__ out) {
  __shared__ float lp[TSTEPS][NSEQ][12];     // 96KB normalized log-probs
  __shared__ float alpha[2][NSEQ][CTC_S];
  __shared__ int ext[NSEQ][CTC_S];
  __shared__ unsigned char allow[NSEQ][CTC_S];
  __shared__ unsigned char validm[NSEQ][CTC_S];
  __shared__ int tlsh[NSEQ];
  __shared__ float logp_sh[NSEQ];

  int tid = threadIdx.x;

  // phase 1: parallel log-softmax for all 2048 rows
  for (int r = tid; r < TSTEPS * NSEQ; r += 576) {
    const float* p = preds + (size_t)r * 12;
    float mx = p[0];
#pragma unroll
    for (int k = 1; k < 12; ++k) mx = fmaxf(mx, p[k]);
    float ssum = 0.f;
#pragma unroll
    for (int k = 0; k < 12; ++k) ssum += __expf(p[k] - mx);
    float ls = mx + __logf(ssum);
    int t = r >> 5, b = r & 31;
#pragma unroll
    for (int k = 0; k < 12; ++k) lp[t][b][k] = p[k] - ls;
  }
  if (tid < NSEQ) tlsh[tid] = text_len[tid];
  __syncthreads();

  int b = tid & 31, sIdx = tid >> 5;
  bool active = sIdx < CTC_S;

  if (active) {
    int tl = tlsh[b];
    int off = 0;
    for (int i = 0; i < b; ++i) off += tlsh[i];
    int e = 0;
    if (sIdx & 1) {
      int lbl = (sIdx - 1) >> 1;
      int idx = off + lbl;
      if (idx > 255) idx = 255;
      e = (lbl < tl) ? text[idx] : 0;
    }
    ext[b][sIdx] = e;
    validm[b][sIdx] = (sIdx < 2 * tl + 1) ? 1 : 0;
  }
  __syncthreads();
  if (active) {
    int e = ext[b][sIdx];
    bool same2 = (sIdx >= 2) && (e == ext[b][sIdx - 2]);
    allow[b][sIdx] = ((sIdx >= 2) && (e != 0) && !same2) ? 1 : 0;
    // init t = 0 (buffer 0)
    float a = -1e30f;
    if (sIdx == 0) a = lp[0][b][0];
    else if (sIdx == 1 && tlsh[b] > 0) a = lp[0][b][ext[b][1]];
    alpha[0][b][sIdx] = a;
  }
  __syncthreads();

  // scan: one barrier per step, ping-pong buffers
  for (int t = 1; t < TSTEPS; ++t) {
    int cur = (t - 1) & 1, nxt = t & 1;
    if (active) {
      float a = alpha[cur][b][sIdx];
      float a1 = (sIdx >= 1) ? alpha[cur][b][sIdx - 1] : -1e30f;
      float a2 = (sIdx >= 2 && allow[b][sIdx]) ? alpha[cur][b][sIdx - 2] : -1e30f;
      float m = fmaxf(a, fmaxf(a1, a2));
      float ssum = __expf(a - m) + __expf(a1 - m) + __expf(a2 - m);
      float nv = m + __logf(ssum) + lp[t][b][ext[b][sIdx]];
      alpha[nxt][b][sIdx] = validm[b][sIdx] ? nv : -1e30f;
    }
    __syncthreads();
  }

  // final: T-1 = 63 (odd) -> buffer 1
  if (tid < NSEQ) {
    int tl = tlsh[b];
    float a1 = alpha[1][b][2 * tl];
    float a2 = (tl > 0) ? alpha[1][b][2 * tl - 1] : -1e30f;
    float m = fmaxf(a1, a2);
    logp_sh[b] = m + __logf(__expf(a1 - m) + __expf(a2 - m));
  }
  __syncthreads();
  if (tid == 0) {
    float ssum = 0.f;
    for (int i = 0; i < NSEQ; ++i) ssum += logp_sh[i];
    out[0] = -ssum / (float)NSEQ;
  }
}

// ---------------- launch ----------------
extern "C" void kernel_launch(void* const* d_in, const int* in_sizes, int n_in,
                              void* d_out, int out_size, void* d_ws, size_t ws_size,
                              hipStream_t stream) {
  (void)in_sizes; (void)n_in; (void)out_size; (void)ws_size;
  const float* base_feat = (const float*)d_in[0];
  const int* text = (const int*)d_in[1];
  const int* text_len = (const int*)d_in[2];
  const float* rois = (const float*)d_in[3];
  const float* l1_fw_W_ih = (const float*)d_in[4];
  const float* l1_fw_W_hh = (const float*)d_in[5];
  const float* l1_fw_b_ih = (const float*)d_in[6];
  const float* l1_fw_b_hh = (const float*)d_in[7];
  const float* l1_bw_W_ih = (const float*)d_in[8];
  const float* l1_bw_W_hh = (const float*)d_in[9];
  const float* l1_bw_b_ih = (const float*)d_in[10];
  const float* l1_bw_b_hh = (const float*)d_in[11];
  const float* l2_fw_W_ih = (const float*)d_in[12];
  const float* l2_fw_W_hh = (const float*)d_in[13];
  const float* l2_fw_b_ih = (const float*)d_in[14];
  const float* l2_fw_b_hh = (const float*)d_in[15];
  const float* l2_bw_W_ih = (const float*)d_in[16];
  const float* l2_bw_W_hh = (const float*)d_in[17];
  const float* l2_bw_b_ih = (const float*)d_in[18];
  const float* l2_bw_b_hh = (const float*)d_in[19];
  const float* W_emb1 = (const float*)d_in[20];
  const float* b_emb1 = (const float*)d_in[21];
  const float* W_emb2 = (const float*)d_in[22];
  const float* b_emb2 = (const float*)d_in[23];

  float* ws = (float*)d_ws;
  unsigned short* xgb  = (unsigned short*)(ws + OFF_XGB);
  unsigned short* rnnb = (unsigned short*)(ws + OFF_RNNB);
  unsigned short* w12b = (unsigned short*)(ws + OFF_W12B);
  unsigned short* w22b = (unsigned short*)(ws + OFF_W22B);
  unsigned short* we1b = (unsigned short*)(ws + OFF_WE1B);
  unsigned short* we2b = (unsigned short*)(ws + OFF_WE2B);
  float* pb1 = ws + OFF_PB1;
  float* pb2 = ws + OFF_PB2;
  unsigned char* w8l1f = (unsigned char*)(ws + OFF_W8L1F);
  unsigned char* w8l1b = (unsigned char*)(ws + OFF_W8L1B);
  unsigned char* w8l2f = (unsigned char*)(ws + OFF_W8L2F);
  unsigned char* w8l2b = (unsigned char*)(ws + OFF_W8L2B);
  unsigned short* hcb1 = (unsigned short*)(ws + OFF_HCB1);
  unsigned short* hcb2 = (unsigned short*)(ws + OFF_HCB2);
  unsigned short* h1b  = (unsigned short*)(ws + OFF_H1B);
  float* preds = ws + OFF_PREDS;

  // 0) all weight/bias prep in one launch
  prep_kernel<<<3734, 256, 0, stream>>>(
      l1_fw_W_ih, l1_bw_W_ih, l2_fw_W_ih, l2_bw_W_ih, W_emb1, W_emb2,
      l1_fw_W_hh, l1_bw_W_hh, l2_fw_W_hh, l2_bw_W_hh,
      l1_fw_b_ih, l1_fw_b_hh, l1_bw_b_ih, l1_bw_b_hh,
      l2_fw_b_ih, l2_fw_b_hh, l2_bw_b_ih, l2_bw_b_hh,
      w12b, w22b, we1b, we2b, w8l1f, w8l1b, w8l2f, w8l2b, pb1, pb2);

  // 1) ROI max pool -> rnn bf16 [2048][1024]
  roi_pool_kernel<<<dim3(32, 256), 256, 0, stream>>>(base_feat, rois, rnnb);

  // 2) xg layer1, both dirs in one launch (mode 5)
  gemm_bf16<<<dim3(16, 16), 256, 0, stream>>>(w12b, rnnb, nullptr, xgb,
      2048, 2048, 1024, pb1, nullptr, 5);

  // 3) layer-1 recurrence
  lstm_layer8<<<4, 512, 0, stream>>>(xgb, w8l1f, w8l1b, hcb1);

  // 4) h1 = hcat1 @ W_emb1^T + b_emb1 -> bf16 [2048][256] (pi-cols cancel)
  gemm_bf16<<<dim3(2, 16), 256, 0, stream>>>(hcb1, we1b, nullptr, h1b,
      2048, 256, 512, nullptr, b_emb1, 1);

  // 5) xg layer2 (mode 5)
  gemm_bf16<<<dim3(16, 16), 256, 0, stream>>>(w22b, h1b, nullptr, xgb,
      2048, 2048, 256, pb2, nullptr, 5);

  // 6) layer-2 recurrence
  lstm_layer8<<<4, 512, 0, stream>>>(xgb, w8l2f, w8l2b, hcb2);

  // 7) preds = hcat2 @ W_emb2^T + b_emb2 (f32, N=12 guarded, pi-cols cancel)
  gemm_bf16<<<dim3(1, 16), 256, 0, stream>>>(hcb2, we2b, preds, nullptr,
      2048, 12, 512, nullptr, b_emb2, 0);

  // 8) log-softmax + CTC
  ctc_kernel<<<1, 576, 0, stream>>>(preds, text, text_len, (float*)d_out);
}